// Round 7
// baseline (2544.736 us; speedup 1.0000x reference)
//
#include <hip/hip_runtime.h>
#include <math.h>

#define EMBED   768
#define HEADS   12
#define DEPTH   12
#define TOKS    32
#define NTOK    1024
#define WINSZ   14
#define NWIN    9
#define WTOK    1764        // 9*196
#define WN      196
#define MLPDIM  3072
#define OUTC    256
#define LNEPS   1e-6f

typedef __attribute__((ext_vector_type(8))) short short8;
typedef __attribute__((ext_vector_type(4))) float float4v;

// pin instruction order: nothing may be scheduled across this point
#define SBAR __builtin_amdgcn_sched_barrier(0)

__device__ __forceinline__ unsigned short f2bf(float f) {
    unsigned u = __float_as_uint(f);
    unsigned r = (u + 0x7fffu + ((u >> 16) & 1u)) >> 16;
    return (unsigned short)r;
}
__device__ __forceinline__ float bf2f(unsigned short s) {
    return __uint_as_float((unsigned)s << 16);
}
// packed f32->bf16 (RNE, identical to f2bf)
__device__ __forceinline__ unsigned cvtpk(float a, float b) {
    unsigned r;
    asm("v_cvt_pk_bf16_f32 %0, %1, %2" : "=v"(r) : "v"(a), "v"(b));
    return r;
}
__device__ __forceinline__ short8 pk8(float4 a, float4 b) {
    union { unsigned u[4]; short8 s; } t;
    t.u[0] = cvtpk(a.x, a.y); t.u[1] = cvtpk(a.z, a.w);
    t.u[2] = cvtpk(b.x, b.y); t.u[3] = cvtpk(b.z, b.w);
    return t.s;
}
// global row p (0..1023) -> window-token index
__device__ __forceinline__ int winidx(int p) {
    int gy = p >> 5, gx = p & 31;
    return ((gy / WINSZ) * 3 + gx / WINSZ) * WN + (gy % WINSZ) * WINSZ + (gx % WINSZ);
}

// ---------------- f32 -> bf16 conversion (fallback path only) --------------
__global__ void f2b4(const float* __restrict__ in, unsigned short* __restrict__ out, int n4) {
    int i = blockIdx.x * blockDim.x + threadIdx.x;
    if (i >= n4) return;
    float4 v = ((const float4*)in)[i];
    ushort4 o;
    o.x = f2bf(v.x); o.y = f2bf(v.y); o.z = f2bf(v.z); o.w = f2bf(v.w);
    ((ushort4*)out)[i] = o;
}

// whole-model weight conversion in ONE launch. 1 float4/thread, fully
// contiguous (measured-best layout). All range boundaries are multiples of
// 256 so the source select is block-uniform. Total 21577728 float4s.
__global__ __launch_bounds__(256) void convw_all(
        const float* __restrict__ q,  const float* __restrict__ pr,
        const float* __restrict__ m1, const float* __restrict__ m2,
        const float* __restrict__ pw, const float* __restrict__ n1,
        const float* __restrict__ n2,
        unsigned short* __restrict__ oq,  unsigned short* __restrict__ opr,
        unsigned short* __restrict__ om1, unsigned short* __restrict__ om2,
        unsigned short* __restrict__ opw, unsigned short* __restrict__ on1,
        unsigned short* __restrict__ on2) {
    long long i = (long long)blockIdx.x * 256 + threadIdx.x;   // float4 units
    const float* s; unsigned short* o; long long off;
    if (i < 5308416LL)       { s = q;  o = oq;  off = i; }
    else if (i < 7077888LL)  { s = pr; o = opr; off = i - 5308416LL; }
    else if (i < 14155776LL) { s = m1; o = om1; off = i - 7077888LL; }
    else if (i < 21233664LL) { s = m2; o = om2; off = i - 14155776LL; }
    else if (i < 21381120LL) { s = pw; o = opw; off = i - 21233664LL; }
    else if (i < 21430272LL) { s = n1; o = on1; off = i - 21381120LL; }
    else                     { s = n2; o = on2; off = i - 21430272LL; }
    float4 v = ((const float4*)s)[off];
    ushort4 w;
    w.x = f2bf(v.x); w.y = f2bf(v.y); w.z = f2bf(v.z); w.w = f2bf(v.w);
    ((ushort4*)o)[off] = w;
}

// fallback per-layer weight conversion (only used if workspace is small)
__global__ void convw4(const float* __restrict__ a, const float* __restrict__ b,
                       const float* __restrict__ c, const float* __restrict__ d,
                       unsigned short* __restrict__ oa, unsigned short* __restrict__ ob,
                       unsigned short* __restrict__ oc, unsigned short* __restrict__ od) {
    int i = blockIdx.x * blockDim.x + threadIdx.x;   // float4 units, total 1769472
    const float* s; unsigned short* o; int off;
    if (i < 442368)       { s = a; o = oa; off = i; }
    else if (i < 589824)  { s = b; o = ob; off = i - 442368; }
    else if (i < 1179648) { s = c; o = oc; off = i - 589824; }
    else                  { s = d; o = od; off = i - 1179648; }
    float4 v = ((const float4*)s)[off];
    ushort4 w;
    w.x = f2bf(v.x); w.y = f2bf(v.y); w.z = f2bf(v.z); w.w = f2bf(v.w);
    ((ushort4*)o)[off] = w;
}

// zero the pad rows of the windowed LN buffer (once)
__global__ __launch_bounds__(256) void zero_pads(unsigned short* __restrict__ XWw) {
    int t = blockIdx.x;                    // 0..1763
    int w = t / WN, r = t % WN;
    int gy = (w / 3) * WINSZ + r / WINSZ, gx = (w % 3) * WINSZ + r % WINSZ;
    if (gy < TOKS && gx < TOKS) return;
    for (int c = threadIdx.x; c < EMBED; c += 256) XWw[(size_t)t * EMBED + c] = 0;
}

// ---------------- register-direct MFMA GEMM, depth-2 K pipeline ------------
// C[M,N] = A[M,K] @ B[N,K]^T + bias. Barrier-free, LDS-free; 4 independent
// waves; block tile 64x64 (wave tile 32x32). 3-slot rolling register buffer,
// statically indexed; sched_barrier(0) after each prefetch PINS the loads
// before the MFMA cluster (compiler otherwise sinks them to use: VGPR=40).
// OMODE: 0 = f32 out, 2 = bf16+GELU out, 3 = qkv split (bf16 Q/K + transposed V)
// SPLIT>1: grid.z splits K; partial f32 written to Cout + z*M*N (no bias).
#define LDT(S, KO) do {                                         \
    _Pragma("unroll")                                           \
    for (int i_ = 0; i_ < 2; i_++) {                            \
        a_##S[i_][0] = *(const short8*)(ap[i_] + (KO));         \
        a_##S[i_][1] = *(const short8*)(ap[i_] + (KO) + 32); }  \
    _Pragma("unroll")                                           \
    for (int j_ = 0; j_ < 2; j_++) {                            \
        b_##S[j_][0] = *(const short8*)(bp[j_] + (KO));         \
        b_##S[j_][1] = *(const short8*)(bp[j_] + (KO) + 32); }  \
} while (0)

#define MFMA_SLOT(S) do {                                       \
    _Pragma("unroll")                                           \
    for (int h_ = 0; h_ < 2; h_++)                              \
        _Pragma("unroll")                                       \
        for (int i_ = 0; i_ < 2; i_++)                          \
            _Pragma("unroll")                                   \
            for (int j_ = 0; j_ < 2; j_++)                      \
                acc[i_][j_] = __builtin_amdgcn_mfma_f32_16x16x32_bf16( \
                    a_##S[i_][h_], b_##S[j_][h_], acc[i_][j_], 0, 0, 0); \
} while (0)

template<int OMODE, int SPLIT, int NT>
__global__ __launch_bounds__(256) void gemm_rd(
        const unsigned short* __restrict__ A, const unsigned short* __restrict__ B,
        const float* __restrict__ bias, void* __restrict__ Cout,
        int M, int N, int K,
        unsigned short* __restrict__ vout, int VN, int VNP) {
    const int tid = threadIdx.x, lane = tid & 63, wave = tid >> 6;
    const int wm = wave >> 1, wn = wave & 1;
    const int l15 = lane & 15, q4 = lane >> 4;
    const int m0 = blockIdx.y * 64 + wm * 32;
    const int n0 = blockIdx.x * 64 + wn * 32;
    const int kb = blockIdx.z * (NT * 64);

    const unsigned short* ap[2];
#pragma unroll
    for (int i = 0; i < 2; i++) {
        int gm = m0 + i * 16 + l15; if (gm >= M) gm = M - 1;
        ap[i] = A + (size_t)gm * K + kb + q4 * 8;
    }
    const unsigned short* bp[2];
#pragma unroll
    for (int j = 0; j < 2; j++) {
        int gn = n0 + j * 16 + l15;
        bp[j] = B + (size_t)gn * K + kb + q4 * 8;
    }

    float4v acc[2][2];
#pragma unroll
    for (int i = 0; i < 2; i++)
#pragma unroll
        for (int j = 0; j < 2; j++) acc[i][j] = (float4v){0.f, 0.f, 0.f, 0.f};

    short8 a_0[2][2], b_0[2][2];
    short8 a_1[2][2], b_1[2][2];
    short8 a_2[2][2], b_2[2][2];

    LDT(0, 0);
    LDT(1, 64);
    SBAR;
    // unrolled-by-3 main loop; invariant at head: slot0 = tile k, slot1 = tile k+1
#pragma unroll
    for (int k = 0; k + 3 < NT; k += 3) {
        LDT(2, (k + 2) * 64); SBAR; MFMA_SLOT(0); SBAR;
        LDT(0, (k + 3) * 64); SBAR; MFMA_SLOT(1); SBAR;
        LDT(1, (k + 4) * 64); SBAR; MFMA_SLOT(2); SBAR;
    }
    // tail: slots 0,1 hold tiles NT-3, NT-2
    LDT(2, (NT - 1) * 64); SBAR;
    MFMA_SLOT(0); MFMA_SLOT(1); MFMA_SLOT(2);

    if (SPLIT > 1) {
        float* P = (float*)Cout + (size_t)blockIdx.z * M * N;
#pragma unroll
        for (int i = 0; i < 2; i++)
#pragma unroll
            for (int r = 0; r < 4; r++) {
                int m = m0 + i * 16 + q4 * 4 + r;
                if (m >= M) continue;
#pragma unroll
                for (int j = 0; j < 2; j++)
                    P[(size_t)m * N + n0 + j * 16 + l15] = acc[i][j][r];
            }
        return;
    }
#pragma unroll
    for (int i = 0; i < 2; i++) {
        int mb = m0 + i * 16 + q4 * 4;
#pragma unroll
        for (int j = 0; j < 2; j++) {
            int n = n0 + j * 16 + l15;
            float bv = bias ? bias[n] : 0.f;
            if (OMODE == 3 && n >= 1536) {
                int nn = n - 1536;
                int head = nn >> 6, dd = nn & 63;
                if (mb + 3 < M) {
                    // 4 consecutive mt (VN % 4 == 0, mb % 4 == 0): one 8B store
                    int win = mb / VN, mt = mb - win * VN;
                    ushort4 o;
                    o.x = f2bf(acc[i][j][0] + bv);
                    o.y = f2bf(acc[i][j][1] + bv);
                    o.z = f2bf(acc[i][j][2] + bv);
                    o.w = f2bf(acc[i][j][3] + bv);
                    *(ushort4*)(vout + (size_t)((win * HEADS + head) * 64 + dd) * VNP + mt) = o;
                } else {
#pragma unroll
                    for (int r = 0; r < 4; r++) {
                        int m = mb + r;
                        if (m >= M) continue;
                        int win = m / VN, mt = m - win * VN;
                        vout[(size_t)((win * HEADS + head) * 64 + dd) * VNP + mt] =
                            f2bf(acc[i][j][r] + bv);
                    }
                }
                continue;
            }
#pragma unroll
            for (int r = 0; r < 4; r++) {
                int m = mb + r;
                if (m >= M) continue;
                float v = acc[i][j][r] + bv;
                if (OMODE == 0) {
                    ((float*)Cout)[(size_t)m * N + n] = v;
                } else if (OMODE == 2) {
                    v = 0.5f * v * (1.f + erff(v * 0.70710678118654752f));
                    ((unsigned short*)Cout)[(size_t)m * N + n] = f2bf(v);
                } else {  // OMODE 3, n < 1536
                    ((unsigned short*)Cout)[(size_t)m * 2304 + n] = f2bf(v);
                }
            }
        }
    }
}

// ---------------- fused reduce + bias + residual + LayerNorm ---------------
// One block per global row p (1024 rows, 256 thr, 3 elems/thr, C=768).
// h = sum_z part[z][tp] + bias + (extra? extra[p]) + (addH? H[p]); if S>0 H[p]=h.
// LN(h) -> lnout: lnmode 1 straight bf16 [p]; 2 windowed bf16 [win(p)]; 3 raw bf16(h) [p]
template<int S>
__global__ __launch_bounds__(256) void fuse_ln(
        const float* __restrict__ part, size_t pstride, int partwin,
        const float* __restrict__ extra, const float* __restrict__ bias,
        float* __restrict__ H, int addH,
        const float* __restrict__ lnw, const float* __restrict__ lnb,
        unsigned short* __restrict__ lnout, int lnmode) {
    const int p = blockIdx.x;
    const int tw = winidx(p);
    const int tp = partwin ? tw : p;
    const int c0 = threadIdx.x;
    float h[3];
    float s1 = 0.f, s2 = 0.f;
#pragma unroll
    for (int j = 0; j < 3; j++) {
        int c = c0 + j * 256;
        float v = 0.f;
        if (S > 0) {
            v = part[(size_t)tp * EMBED + c];
#pragma unroll
            for (int z = 1; z < S; z++) v += part[(size_t)z * pstride + (size_t)tp * EMBED + c];
            v += bias[c];
        }
        if (extra) v += extra[(size_t)p * EMBED + c];
        if (addH)  v += H[(size_t)p * EMBED + c];
        h[j] = v;
        if (S > 0) H[(size_t)p * EMBED + c] = v;
        s1 += v; s2 += v * v;
    }
    for (int off = 32; off; off >>= 1) {
        s1 += __shfl_down(s1, off);
        s2 += __shfl_down(s2, off);
    }
    __shared__ float sh1[4], sh2[4];
    __shared__ float smu, srstd;
    int wv = threadIdx.x >> 6, ln = threadIdx.x & 63;
    if (ln == 0) { sh1[wv] = s1; sh2[wv] = s2; }
    __syncthreads();
    if (threadIdx.x == 0) {
        float t1 = sh1[0] + sh1[1] + sh1[2] + sh1[3];
        float t2 = sh2[0] + sh2[1] + sh2[2] + sh2[3];
        float m = t1 / (float)EMBED;
        smu = m; srstd = rsqrtf(t2 / (float)EMBED - m * m + LNEPS);
    }
    __syncthreads();
    float m = smu, r = srstd;
    unsigned short* dst = lnout + (size_t)(lnmode == 2 ? tw : p) * EMBED;
#pragma unroll
    for (int j = 0; j < 3; j++) {
        int c = c0 + j * 256;
        float v = (lnmode == 3) ? h[j] : (h[j] - m) * r * lnw[c] + lnb[c];
        dst[c] = f2bf(v);
    }
}

// ---------------- fused neck reduce + LayerNorm (C=256) --------------------
// mode 0: f32 out [M,C]; mode 1: f32 out transposed [C,M]
template<int S>
__global__ __launch_bounds__(256) void fuse_ln_neck(
        const float* __restrict__ part, const float* __restrict__ w,
        const float* __restrict__ b, float* __restrict__ out, int M, int mode) {
    const int row = blockIdx.x, c = threadIdx.x;
    float v = part[(size_t)row * OUTC + c];
#pragma unroll
    for (int z = 1; z < S; z++)
        v += part[(size_t)z * M * OUTC + (size_t)row * OUTC + c];
    float s1 = v, s2 = v * v;
    for (int off = 32; off; off >>= 1) {
        s1 += __shfl_down(s1, off);
        s2 += __shfl_down(s2, off);
    }
    __shared__ float sh1[4], sh2[4];
    __shared__ float smu, srs;
    int wv = threadIdx.x >> 6, ln = threadIdx.x & 63;
    if (ln == 0) { sh1[wv] = s1; sh2[wv] = s2; }
    __syncthreads();
    if (threadIdx.x == 0) {
        float t1 = sh1[0] + sh1[1] + sh1[2] + sh1[3];
        float t2 = sh2[0] + sh2[1] + sh2[2] + sh2[3];
        float m = t1 / (float)OUTC;
        smu = m; srs = rsqrtf(t2 / (float)OUTC - m * m + LNEPS);
    }
    __syncthreads();
    float res = (v - smu) * srs * w[c] + b[c];
    if (mode == 0) out[(size_t)row * OUTC + c] = res;
    else           out[(size_t)c * M + row] = res;
}

// ---------------- fused MFMA flash attention -------------------------------
template<int N, int HH, int WW, int VNP>
__global__ __launch_bounds__(256) void attn_mfma(
        const unsigned short* __restrict__ qkv, const unsigned short* __restrict__ vt,
        const float* __restrict__ rel_h, const float* __restrict__ rel_w,
        unsigned short* __restrict__ out) {
    constexpr int NT = (N + 63) / 64;
    constexpr int JH = ((2 * HH - 1 + 15) / 16) * 16;
    constexpr int JW = ((2 * WW - 1 + 15) / 16) * 16;
    __shared__ unsigned short Pw[4][16 * 72];
    __shared__ float Dh[4][16][JH];
    __shared__ float Dw[4][16][JW];
    const int tid = threadIdx.x, lane = tid & 63, w = tid >> 6;
    const int l15 = lane & 15, q4 = lane >> 4;
    const int bh = blockIdx.y, winI = bh / HEADS, head = bh % HEADS;
    const int base = winI * N;
    const int q0 = blockIdx.x * 64;

    short8 aq0, aq1;
    {
        int qr = q0 + w * 16 + l15; if (qr >= N) qr = N - 1;
        const unsigned short* qp = qkv + (size_t)(base + qr) * 2304 + head * 64;
        aq0 = *(const short8*)(qp + q4 * 8);
        aq1 = *(const short8*)(qp + 32 + q4 * 8);
    }

#pragma unroll
    for (int s = 0; s < JH / 16; s++) {
        int j = s * 16 + l15; if (j > 2 * HH - 2) j = 2 * HH - 2;
        const float* rp = rel_h + (size_t)j * 64 + q4 * 8;
        float4 r0 = *(const float4*)rp;
        float4 r1 = *(const float4*)(rp + 4);
        float4 r2 = *(const float4*)(rp + 32);
        float4 r3 = *(const float4*)(rp + 36);
        short8 b0 = pk8(r0, r1), b1 = pk8(r2, r3);
        float4v df = (float4v){0.f, 0.f, 0.f, 0.f};
        df = __builtin_amdgcn_mfma_f32_16x16x32_bf16(aq0, b0, df, 0, 0, 0);
        df = __builtin_amdgcn_mfma_f32_16x16x32_bf16(aq1, b1, df, 0, 0, 0);
#pragma unroll
        for (int r = 0; r < 4; r++) Dh[w][q4 * 4 + r][s * 16 + l15] = df[r];
    }
#pragma unroll
    for (int s = 0; s < JW / 16; s++) {
        int j = s * 16 + l15; if (j > 2 * WW - 2) j = 2 * WW - 2;
        const float* rp = rel_w + (size_t)j * 64 + q4 * 8;
        float4 r0 = *(const float4*)rp;
        float4 r1 = *(const float4*)(rp + 4);
        float4 r2 = *(const float4*)(rp + 32);
        float4 r3 = *(const float4*)(rp + 36);
        short8 b0 = pk8(r0, r1), b1 = pk8(r2, r3);
        float4v df = (float4v){0.f, 0.f, 0.f, 0.f};
        df = __builtin_amdgcn_mfma_f32_16x16x32_bf16(aq0, b0, df, 0, 0, 0);
        df = __builtin_amdgcn_mfma_f32_16x16x32_bf16(aq1, b1, df, 0, 0, 0);
#pragma unroll
        for (int r = 0; r < 4; r++) Dw[w][q4 * 4 + r][s * 16 + l15] = df[r];
    }

    int qhv[4], qwv[4];
#pragma unroll
    for (int r = 0; r < 4; r++) {
        int qg = q0 + w * 16 + q4 * 4 + r;
        qhv[r] = qg / WW;
        qwv[r] = qg - qhv[r] * WW;
    }

    float m_r[4], l_r[4];
    float4v acc_o[4];
#pragma unroll
    for (int r = 0; r < 4; r++) { m_r[r] = -1e30f; l_r[r] = 0.f; }
#pragma unroll
    for (int s = 0; s < 4; s++) acc_o[s] = (float4v){0.f, 0.f, 0.f, 0.f};

    const unsigned short* vbase = vt + (size_t)bh * 64 * VNP;
    const unsigned short* kqbase = qkv + (size_t)base * 2304 + 768 + head * 64;

    short8 kc[8];
#pragma unroll
    for (int s = 0; s < 4; s++) {
        int kr = s * 16 + l15; if (kr >= N) kr = N - 1;
        const unsigned short* kp = kqbase + (size_t)kr * 2304;
        kc[2 * s]     = *(const short8*)(kp + q4 * 8);
        kc[2 * s + 1] = *(const short8*)(kp + 32 + q4 * 8);
    }

    for (int kt = 0; kt < NT; kt++) {
        // ---- prefetch V[kt] and K[kt+1]; SBAR pins the issue point ----
        short8 vv[8];
        {
            const unsigned short* vb = vbase + kt * 64;
#pragma unroll
            for (int s2 = 0; s2 < 4; s2++) {
                const unsigned short* vr = vb + (size_t)(s2 * 16 + l15) * VNP;
                vv[2 * s2]     = *(const short8*)(vr + q4 * 8);
                vv[2 * s2 + 1] = *(const short8*)(vr + 32 + q4 * 8);
            }
        }
        short8 kn[8];
        {
            int ktn = (kt + 1 < NT) ? kt + 1 : kt;
#pragma unroll
            for (int s = 0; s < 4; s++) {
                int kr = ktn * 64 + s * 16 + l15; if (kr >= N) kr = N - 1;
                const unsigned short* kp = kqbase + (size_t)kr * 2304;
                kn[2 * s]     = *(const short8*)(kp + q4 * 8);
                kn[2 * s + 1] = *(const short8*)(kp + 32 + q4 * 8);
            }
        }
        SBAR;
        float sv[4][4];
#pragma unroll
        for (int s = 0; s < 4; s++) {
            float4v sf = (float4v){0.f, 0.f, 0.f, 0.f};
            sf = __builtin_amdgcn_mfma_f32_16x16x32_bf16(aq0, kc[2 * s], sf, 0, 0, 0);
            sf = __builtin_amdgcn_mfma_f32_16x16x32_bf16(aq1, kc[2 * s + 1], sf, 0, 0, 0);
            int col = kt * 64 + s * 16 + l15;
            if (col < N) {
                int kh = col / WW, kw = col - kh * WW;
#pragma unroll
                for (int r = 0; r < 4; r++)
                    sv[s][r] = sf[r] * 0.125f
                             + Dh[w][q4 * 4 + r][qhv[r] - kh + HH - 1]
                             + Dw[w][q4 * 4 + r][qwv[r] - kw + WW - 1];
            } else {
#pragma unroll
                for (int r = 0; r < 4; r++) sv[s][r] = -1e30f;
            }
        }
        float p[4][4];
#pragma unroll
        for (int r = 0; r < 4; r++) {
            float t = fmaxf(fmaxf(sv[0][r], sv[1][r]), fmaxf(sv[2][r], sv[3][r]));
#pragma unroll
            for (int off = 1; off < 16; off <<= 1) t = fmaxf(t, __shfl_xor(t, off));
            float mn = fmaxf(m_r[r], t);
            float alpha = __expf(m_r[r] - mn);
            m_r[r] = mn;
            float ps = 0.f;
#pragma unroll
            for (int s = 0; s < 4; s++) { p[s][r] = __expf(sv[s][r] - mn); ps += p[s][r]; }
#pragma unroll
            for (int off = 1; off < 16; off <<= 1) ps += __shfl_xor(ps, off);
            l_r[r] = l_r[r] * alpha + ps;
#pragma unroll
            for (int s = 0; s < 4; s++) acc_o[s][r] *= alpha;
        }
#pragma unroll
        for (int s = 0; s < 4; s++)
#pragma unroll
            for (int r = 0; r < 4; r++)
                Pw[w][(q4 * 4 + r) * 72 + s * 16 + l15] = f2bf(p[s][r]);
        short8 af0 = *(const short8*)(&Pw[w][l15 * 72 + q4 * 8]);
        short8 af1 = *(const short8*)(&Pw[w][l15 * 72 + 32 + q4 * 8]);
#pragma unroll
        for (int s2 = 0; s2 < 4; s2++) {
            acc_o[s2] = __builtin_amdgcn_mfma_f32_16x16x32_bf16(af0, vv[2 * s2], acc_o[s2], 0, 0, 0);
            acc_o[s2] = __builtin_amdgcn_mfma_f32_16x16x32_bf16(af1, vv[2 * s2 + 1], acc_o[s2], 0, 0, 0);
        }
#pragma unroll
        for (int i = 0; i < 8; i++) kc[i] = kn[i];
    }
#pragma unroll
    for (int r = 0; r < 4; r++) {
        int qg = q0 + w * 16 + q4 * 4 + r;
        if (qg >= N) continue;
        float inv = 1.f / l_r[r];
#pragma unroll
        for (int s2 = 0; s2 < 4; s2++)
            out[(size_t)(base + qg) * EMBED + head * 64 + s2 * 16 + l15] =
                f2bf(acc_o[s2][r] * inv);
    }
}

// ---------------- patch-embed im2col (bf16 out) ----------------------------
__global__ void im2col_patch(const float* __restrict__ x, unsigned short* __restrict__ A, int n) {
    int i = blockIdx.x * blockDim.x + threadIdx.x;
    if (i >= n) return;
    int t = i / EMBED, kidx = i % EMBED;
    int c = kidx >> 8, r = kidx & 255;
    int ph = r >> 4, pw = r & 15;
    int ty = t >> 5, tx = t & 31;
    A[i] = f2bf(x[(size_t)c * 512 * 512 + (size_t)(ty * 16 + ph) * 512 + (tx * 16 + pw)]);
}

// ---------------- neck 3x3 conv im2col (bf16 out) --------------------------
__global__ void im2col3(const float* __restrict__ in, unsigned short* __restrict__ out, int n) {
    int i = blockIdx.x * blockDim.x + threadIdx.x;
    if (i >= n) return;
    int p = i / 2304, k = i % 2304;
    int c = k / 9, r9 = k % 9;
    int ky = r9 / 3, kx = r9 % 3;
    int py = p >> 5, px = p & 31;
    int ny = py + ky - 1, nx = px + kx - 1;
    float v = (ny >= 0 && ny < TOKS && nx >= 0 && nx < TOKS)
                ? in[(size_t)(ny * TOKS + nx) * OUTC + c] : 0.f;
    out[i] = f2bf(v);
}

// ---------------- host orchestration ---------------------------------------
extern "C" void kernel_launch(void* const* d_in, const int* in_sizes, int n_in,
                              void* d_out, int out_size, void* d_ws, size_t ws_size,
                              hipStream_t stream) {
    const float* x        = (const float*)d_in[0];
    const float* patch_w  = (const float*)d_in[1];
    const float* patch_b  = (const float*)d_in[2];
    const float* pos      = (const float*)d_in[3];
    const float* qkv_w    = (const float*)d_in[4];
    const float* qkv_b    = (const float*)d_in[5];
    const float* proj_w   = (const float*)d_in[6];
    const float* proj_b   = (const float*)d_in[7];
    const float* n1w      = (const float*)d_in[8];
    const float* n1b      = (const float*)d_in[9];
    const float* n2w      = (const float*)d_in[10];
    const float* n2b      = (const float*)d_in[11];
    const float* mlp_w1   = (const float*)d_in[12];
    const float* mlp_b1   = (const float*)d_in[13];
    const float* mlp_w2   = (const float*)d_in[14];
    const float* mlp_b2   = (const float*)d_in[15];
    const float* rhw      = (const float*)d_in[16];
    const float* rww      = (const float*)d_in[17];
    const float* rhg      = (const float*)d_in[18];
    const float* rwg      = (const float*)d_in[19];
    const float* neck_w1  = (const float*)d_in[20];
    const float* nl1w     = (const float*)d_in[21];
    const float* nl1b     = (const float*)d_in[22];
    const float* neck_w2  = (const float*)d_in[23];
    const float* nl2w     = (const float*)d_in[24];
    const float* nl2b     = (const float*)d_in[25];

    const size_t SZ_QKVW = (size_t)2304 * 768;
    const size_t SZ_PROJ = (size_t)768 * 768;
    const size_t SZ_MLP1 = (size_t)3072 * 768;
    const size_t SZ_MLP2 = (size_t)768 * 3072;

    char* p = (char*)d_ws;
    float* H    = (float*)p;            p += (size_t)NTOK * EMBED * 4;
    unsigned short* QKVb = (unsigned short*)p; p += (size_t)WTOK * 2304 * 2;
    unsigned short* Vt   = (unsigned short*)p; p += (size_t)NWIN * HEADS * 64 * 208 * 2 + 4096;
    float* LNF  = (float*)p;            p += (size_t)NTOK * OUTC * 4;
    unsigned short* XWw = (unsigned short*)p;  p += (size_t)WTOK * EMBED * 2;
    unsigned short* XWs = (unsigned short*)p;  p += (size_t)NTOK * EMBED * 2;
    unsigned short* AOb = (unsigned short*)p;  p += (size_t)WTOK * EMBED * 2;
    float* SPK  = (float*)p;            p += (size_t)16 * 1024 * 1024;
    unsigned short* PWb  = (unsigned short*)p; p += SZ_PROJ * 2;
    unsigned short* NW1b = (unsigned short*)p; p += (size_t)OUTC * 768 * 2;
    unsigned short* NW2b = (unsigned short*)p; p += (size_t)OUTC * 2304 * 2;
    unsigned short* MIDB  = QKVb;   // alias: MLP mid 1024x3072 bf16
    unsigned short* CONVA = QKVb;   // alias: neck im2col 1024x2304 bf16

    // all-layer preconverted weights (if workspace allows)
    unsigned short* WQa = (unsigned short*)p;
    size_t needAll = (size_t)(p - (char*)d_ws) +
                     (SZ_QKVW + SZ_PROJ + SZ_MLP1 + SZ_MLP2) * 2 * DEPTH;
    bool pre = ws_size >= needAll;
    unsigned short *WPa, *W1a, *W2a;
    size_t sQ, sP, s1, s2;
    if (pre) {
        WPa = WQa + SZ_QKVW * DEPTH;
        W1a = WPa + SZ_PROJ * DEPTH;
        W2a = W1a + SZ_MLP1 * DEPTH;
        sQ = SZ_QKVW; sP = SZ_PROJ; s1 = SZ_MLP1; s2 = SZ_MLP2;
    } else {
        WPa = WQa + SZ_QKVW;
        W1a = WPa + SZ_PROJ;
        W2a = W1a + SZ_MLP1;
        sQ = sP = s1 = s2 = 0;
    }

    const int NE = NTOK * EMBED;

    zero_pads<<<WTOK, 256, 0, stream>>>(XWw);
    if (pre) {
        convw_all<<<84288, 256, 0, stream>>>(
            qkv_w, proj_w, mlp_w1, mlp_w2, patch_w, neck_w1, neck_w2,
            WQa, WPa, W1a, W2a, PWb, NW1b, NW2b);
    } else {
        f2b4<<<(EMBED * EMBED / 4 + 255) / 256, 256, 0, stream>>>(patch_w, PWb, EMBED * EMBED / 4);
        f2b4<<<(OUTC * EMBED / 4 + 255) / 256, 256, 0, stream>>>(neck_w1, NW1b, OUTC * EMBED / 4);
        f2b4<<<(OUTC * 2304 / 4 + 255) / 256, 256, 0, stream>>>(neck_w2, NW2b, OUTC * 2304 / 4);
    }

    // ---- patch embed (split-K=2) + fused [sum + patch_b + pos -> H; LN1 -> windowed] ----
    im2col_patch<<<(NE + 255) / 256, 256, 0, stream>>>(x, AOb, NE);
    gemm_rd<0, 2, 6><<<dim3(EMBED / 64, NTOK / 64, 2), 256, 0, stream>>>(
        AOb, PWb, nullptr, SPK, NTOK, EMBED, EMBED, nullptr, 0, 0);
    fuse_ln<2><<<NTOK, 256, 0, stream>>>(
        SPK, (size_t)NTOK * EMBED, 0, pos, patch_b, H, 0, n1w, n1b, XWw, 2);

    for (int i = 0; i < DEPTH; i++) {
        bool glob = (i == 2 || i == 5 || i == 8 || i == 11);
        const unsigned short* wq = WQa + sQ * i;
        const unsigned short* wp = WPa + sP * i;
        const unsigned short* w1 = W1a + s1 * i;
        const unsigned short* w2 = W2a + s2 * i;
        if (!pre)
            convw4<<<(1769472 + 255) / 256, 256, 0, stream>>>(
                qkv_w + (size_t)i * SZ_QKVW, proj_w + (size_t)i * SZ_PROJ,
                mlp_w1 + (size_t)i * SZ_MLP1, mlp_w2 + (size_t)i * SZ_MLP2,
                WQa, WPa, W1a, W2a);

        if (!glob) {
            gemm_rd<3, 1, 12><<<dim3(2304 / 64, (WTOK + 63) / 64), 256, 0, stream>>>(
                XWw, wq, qkv_b + i * 2304, QKVb, WTOK, 2304, EMBED, Vt, WN, 208);
            attn_mfma<WN, WINSZ, WINSZ, 208><<<dim3(4, NWIN * HEADS), 256, 0, stream>>>(
                QKVb, Vt, rhw + (size_t)i * 27 * 64, rww + (size_t)i * 27 * 64, AOb);
            gemm_rd<0, 2, 6><<<dim3(EMBED / 64, (WTOK + 63) / 64, 2), 256, 0, stream>>>(
                AOb, wp, nullptr, SPK, WTOK, EMBED, EMBED, nullptr, 0, 0);
            fuse_ln<2><<<NTOK, 256, 0, stream>>>(
                SPK, (size_t)WTOK * EMBED, 1, nullptr, proj_b + i * EMBED, H, 1,
                n2w + i * EMBED, n2b + i * EMBED, XWs, 1);
        } else {
            gemm_rd<3, 1, 12><<<dim3(2304 / 64, NTOK / 64), 256, 0, stream>>>(
                XWs, wq, qkv_b + i * 2304, QKVb, NTOK, 2304, EMBED, Vt, NTOK, NTOK);
            attn_mfma<NTOK, TOKS, TOKS, NTOK><<<dim3(16, HEADS), 256, 0, stream>>>(
                QKVb, Vt, rhg + (size_t)i * 63 * 64, rwg + (size_t)i * 63 * 64, AOb);
            gemm_rd<0, 2, 6><<<dim3(EMBED / 64, NTOK / 64, 2), 256, 0, stream>>>(
                AOb, wp, nullptr, SPK, NTOK, EMBED, EMBED, nullptr, 0, 0);
            fuse_ln<2><<<NTOK, 256, 0, stream>>>(
                SPK, (size_t)NTOK * EMBED, 0, nullptr, proj_b + i * EMBED, H, 1,
                n2w + i * EMBED, n2b + i * EMBED, XWs, 1);
        }
        // MLP
        gemm_rd<2, 1, 12><<<dim3(MLPDIM / 64, NTOK / 64), 256, 0, stream>>>(
            XWs, w1, mlp_b1 + i * MLPDIM, MIDB, NTOK, MLPDIM, EMBED, nullptr, 0, 0);
        gemm_rd<0, 4, 12><<<dim3(EMBED / 64, NTOK / 64, 4), 256, 0, stream>>>(
            MIDB, w2, nullptr, SPK, NTOK, EMBED, MLPDIM, nullptr, 0, 0);
        int nlnmode; const float* nw; const float* nb; unsigned short* ndst;
        if (i == DEPTH - 1) { nlnmode = 3; nw = n1w; nb = n1b; ndst = XWs; }
        else {
            bool nglob = (i + 1 == 2 || i + 1 == 5 || i + 1 == 8 || i + 1 == 11);
            nlnmode = nglob ? 1 : 2;
            nw = n1w + (size_t)(i + 1) * EMBED; nb = n1b + (size_t)(i + 1) * EMBED;
            ndst = nglob ? XWs : XWw;
        }
        fuse_ln<4><<<NTOK, 256, 0, stream>>>(
            SPK, (size_t)NTOK * EMBED, 0, nullptr, mlp_b2 + i * EMBED, H, 1,
            nw, nb, ndst, nlnmode);
    }

    // ---- neck ----
    gemm_rd<0, 4, 3><<<dim3(OUTC / 64, NTOK / 64, 4), 256, 0, stream>>>(
        XWs, NW1b, nullptr, SPK, NTOK, OUTC, EMBED, nullptr, 0, 0);
    fuse_ln_neck<4><<<NTOK, 256, 0, stream>>>(SPK, nl1w, nl1b, LNF, NTOK, 0);
    im2col3<<<(NTOK * 2304 + 255) / 256, 256, 0, stream>>>(LNF, CONVA, NTOK * 2304);
    gemm_rd<0, 6, 6><<<dim3(OUTC / 64, NTOK / 64, 6), 256, 0, stream>>>(
        CONVA, NW2b, nullptr, SPK, NTOK, OUTC, 2304, nullptr, 0, 0);
    fuse_ln_neck<6><<<NTOK, 256, 0, stream>>>(SPK, nl2w, nl2b, (float*)d_out, NTOK, 1);
}

// Round 8
// 2461.673 us; speedup vs baseline: 1.0337x; 1.0337x over previous
//
#include <hip/hip_runtime.h>
#include <math.h>

#define EMBED   768
#define HEADS   12
#define DEPTH   12
#define TOKS    32
#define NTOK    1024
#define WINSZ   14
#define NWIN    9
#define WTOK    1764        // 9*196
#define WN      196
#define MLPDIM  3072
#define OUTC    256
#define LNEPS   1e-6f

typedef __attribute__((ext_vector_type(8))) short short8;
typedef __attribute__((ext_vector_type(4))) float float4v;

__device__ __forceinline__ unsigned short f2bf(float f) {
    unsigned u = __float_as_uint(f);
    unsigned r = (u + 0x7fffu + ((u >> 16) & 1u)) >> 16;
    return (unsigned short)r;
}
__device__ __forceinline__ float bf2f(unsigned short s) {
    return __uint_as_float((unsigned)s << 16);
}
// packed f32->bf16 (RNE, identical to f2bf)
__device__ __forceinline__ unsigned cvtpk(float a, float b) {
    unsigned r;
    asm("v_cvt_pk_bf16_f32 %0, %1, %2" : "=v"(r) : "v"(a), "v"(b));
    return r;
}
__device__ __forceinline__ short8 pk8(float4 a, float4 b) {
    union { unsigned u[4]; short8 s; } t;
    t.u[0] = cvtpk(a.x, a.y); t.u[1] = cvtpk(a.z, a.w);
    t.u[2] = cvtpk(b.x, b.y); t.u[3] = cvtpk(b.z, b.w);
    return t.s;
}
// global row p (0..1023) -> window-token index
__device__ __forceinline__ int winidx(int p) {
    int gy = p >> 5, gx = p & 31;
    return ((gy / WINSZ) * 3 + gx / WINSZ) * WN + (gy % WINSZ) * WINSZ + (gx % WINSZ);
}

// ---------------- f32 -> bf16 conversion (fallback path only) --------------
__global__ void f2b4(const float* __restrict__ in, unsigned short* __restrict__ out, int n4) {
    int i = blockIdx.x * blockDim.x + threadIdx.x;
    if (i >= n4) return;
    float4 v = ((const float4*)in)[i];
    ushort4 o;
    o.x = f2bf(v.x); o.y = f2bf(v.y); o.z = f2bf(v.z); o.w = f2bf(v.w);
    ((ushort4*)out)[i] = o;
}

// whole-model weight conversion in ONE launch. 1 float4/thread, fully
// contiguous (measured-best layout). All range boundaries are multiples of
// 256 so the source select is block-uniform. Total 21577728 float4s.
__global__ __launch_bounds__(256) void convw_all(
        const float* __restrict__ q,  const float* __restrict__ pr,
        const float* __restrict__ m1, const float* __restrict__ m2,
        const float* __restrict__ pw, const float* __restrict__ n1,
        const float* __restrict__ n2,
        unsigned short* __restrict__ oq,  unsigned short* __restrict__ opr,
        unsigned short* __restrict__ om1, unsigned short* __restrict__ om2,
        unsigned short* __restrict__ opw, unsigned short* __restrict__ on1,
        unsigned short* __restrict__ on2) {
    long long i = (long long)blockIdx.x * 256 + threadIdx.x;   // float4 units
    const float* s; unsigned short* o; long long off;
    if (i < 5308416LL)       { s = q;  o = oq;  off = i; }
    else if (i < 7077888LL)  { s = pr; o = opr; off = i - 5308416LL; }
    else if (i < 14155776LL) { s = m1; o = om1; off = i - 7077888LL; }
    else if (i < 21233664LL) { s = m2; o = om2; off = i - 14155776LL; }
    else if (i < 21381120LL) { s = pw; o = opw; off = i - 21233664LL; }
    else if (i < 21430272LL) { s = n1; o = on1; off = i - 21381120LL; }
    else                     { s = n2; o = on2; off = i - 21430272LL; }
    float4 v = ((const float4*)s)[off];
    ushort4 w;
    w.x = f2bf(v.x); w.y = f2bf(v.y); w.z = f2bf(v.z); w.w = f2bf(v.w);
    ((ushort4*)o)[off] = w;
}

// fallback per-layer weight conversion (only used if workspace is small)
__global__ void convw4(const float* __restrict__ a, const float* __restrict__ b,
                       const float* __restrict__ c, const float* __restrict__ d,
                       unsigned short* __restrict__ oa, unsigned short* __restrict__ ob,
                       unsigned short* __restrict__ oc, unsigned short* __restrict__ od) {
    int i = blockIdx.x * blockDim.x + threadIdx.x;   // float4 units, total 1769472
    const float* s; unsigned short* o; int off;
    if (i < 442368)       { s = a; o = oa; off = i; }
    else if (i < 589824)  { s = b; o = ob; off = i - 442368; }
    else if (i < 1179648) { s = c; o = oc; off = i - 589824; }
    else                  { s = d; o = od; off = i - 1179648; }
    float4 v = ((const float4*)s)[off];
    ushort4 w;
    w.x = f2bf(v.x); w.y = f2bf(v.y); w.z = f2bf(v.z); w.w = f2bf(v.w);
    ((ushort4*)o)[off] = w;
}

// zero the pad rows of the windowed LN buffer (once)
__global__ __launch_bounds__(256) void zero_pads(unsigned short* __restrict__ XWw) {
    int t = blockIdx.x;                    // 0..1763
    int w = t / WN, r = t % WN;
    int gy = (w / 3) * WINSZ + r / WINSZ, gx = (w % 3) * WINSZ + r % WINSZ;
    if (gy < TOKS && gx < TOKS) return;
    for (int c = threadIdx.x; c < EMBED; c += 256) XWw[(size_t)t * EMBED + c] = 0;
}

// ---------------- register-direct MFMA GEMM, depth-2 K pipeline ------------
// C[M,N] = A[M,K] @ B[N,K]^T + bias. Barrier-free, LDS-free; 4 independent
// waves; block tile 64x64 (wave tile 32x32). 3-slot rolling register buffer,
// statically indexed. XCD-aware bijective block swizzle (m204) with m-fastest
// decode: each XCD works a contiguous run of m-tiles for few n-panels ->
// B panels stay resident in that XCD's private L2 (first-touch L3 misses
// become L2 hits; this kernel is load-latency-bound).
// OMODE: 0 = f32 out, 2 = bf16+GELU out, 3 = qkv split (bf16 Q/K + transposed V)
// SPLIT>1: grid.z splits K; partial f32 written to Cout + z*M*N (no bias).
#define LDT(S, KO) do {                                         \
    _Pragma("unroll")                                           \
    for (int i_ = 0; i_ < 2; i_++) {                            \
        a_##S[i_][0] = *(const short8*)(ap[i_] + (KO));         \
        a_##S[i_][1] = *(const short8*)(ap[i_] + (KO) + 32); }  \
    _Pragma("unroll")                                           \
    for (int j_ = 0; j_ < 2; j_++) {                            \
        b_##S[j_][0] = *(const short8*)(bp[j_] + (KO));         \
        b_##S[j_][1] = *(const short8*)(bp[j_] + (KO) + 32); }  \
} while (0)

#define MFMA_SLOT(S) do {                                       \
    _Pragma("unroll")                                           \
    for (int h_ = 0; h_ < 2; h_++)                              \
        _Pragma("unroll")                                       \
        for (int i_ = 0; i_ < 2; i_++)                          \
            _Pragma("unroll")                                   \
            for (int j_ = 0; j_ < 2; j_++)                      \
                acc[i_][j_] = __builtin_amdgcn_mfma_f32_16x16x32_bf16( \
                    a_##S[i_][h_], b_##S[j_][h_], acc[i_][j_], 0, 0, 0); \
} while (0)

template<int OMODE, int SPLIT, int NT>
__global__ __launch_bounds__(256) void gemm_rd(
        const unsigned short* __restrict__ A, const unsigned short* __restrict__ B,
        const float* __restrict__ bias, void* __restrict__ Cout,
        int M, int N, int K,
        unsigned short* __restrict__ vout, int VN, int VNP) {
    const int tid = threadIdx.x, lane = tid & 63, wave = tid >> 6;
    const int wm = wave >> 1, wn = wave & 1;
    const int l15 = lane & 15, q4 = lane >> 4;

    // ---- XCD-aware bijective swizzle (m204), m-fastest decode ----
    const int gx = gridDim.x, gy = gridDim.y;
    const int nb = gx * gy;
    const int f  = blockIdx.y * gx + blockIdx.x;   // HW dispatch order (x fastest)
    const int qq = nb >> 3, rr = nb & 7;
    const int xcd = f & 7, sl = f >> 3;
    const int wg = (xcd < rr) ? xcd * (qq + 1) + sl
                              : rr * (qq + 1) + (xcd - rr) * qq + sl;
    const int bn = wg / gy;          // n-panel index (slow within XCD chunk)
    const int bm = wg - bn * gy;     // m index (fast within XCD chunk)

    const int m0 = bm * 64 + wm * 32;
    const int n0 = bn * 64 + wn * 32;
    const int kb = blockIdx.z * (NT * 64);

    const unsigned short* ap[2];
#pragma unroll
    for (int i = 0; i < 2; i++) {
        int gm = m0 + i * 16 + l15; if (gm >= M) gm = M - 1;
        ap[i] = A + (size_t)gm * K + kb + q4 * 8;
    }
    const unsigned short* bp[2];
#pragma unroll
    for (int j = 0; j < 2; j++) {
        int gn = n0 + j * 16 + l15;
        bp[j] = B + (size_t)gn * K + kb + q4 * 8;
    }

    float4v acc[2][2];
#pragma unroll
    for (int i = 0; i < 2; i++)
#pragma unroll
        for (int j = 0; j < 2; j++) acc[i][j] = (float4v){0.f, 0.f, 0.f, 0.f};

    short8 a_0[2][2], b_0[2][2];
    short8 a_1[2][2], b_1[2][2];
    short8 a_2[2][2], b_2[2][2];

    LDT(0, 0);
    LDT(1, 64);
    // unrolled-by-3 main loop; invariant at head: slot0 = tile k, slot1 = tile k+1
#pragma unroll
    for (int k = 0; k + 3 < NT; k += 3) {
        LDT(2, (k + 2) * 64); MFMA_SLOT(0);
        LDT(0, (k + 3) * 64); MFMA_SLOT(1);
        LDT(1, (k + 4) * 64); MFMA_SLOT(2);
    }
    // tail: slots 0,1 hold tiles NT-3, NT-2
    LDT(2, (NT - 1) * 64);
    MFMA_SLOT(0); MFMA_SLOT(1); MFMA_SLOT(2);

    if (SPLIT > 1) {
        float* P = (float*)Cout + (size_t)blockIdx.z * M * N;
#pragma unroll
        for (int i = 0; i < 2; i++)
#pragma unroll
            for (int r = 0; r < 4; r++) {
                int m = m0 + i * 16 + q4 * 4 + r;
                if (m >= M) continue;
#pragma unroll
                for (int j = 0; j < 2; j++)
                    P[(size_t)m * N + n0 + j * 16 + l15] = acc[i][j][r];
            }
        return;
    }
#pragma unroll
    for (int i = 0; i < 2; i++) {
        int mb = m0 + i * 16 + q4 * 4;
#pragma unroll
        for (int j = 0; j < 2; j++) {
            int n = n0 + j * 16 + l15;
            float bv = bias ? bias[n] : 0.f;
            if (OMODE == 3 && n >= 1536) {
                int nn = n - 1536;
                int head = nn >> 6, dd = nn & 63;
                if (mb + 3 < M) {
                    // 4 consecutive mt (VN % 4 == 0, mb % 4 == 0): one 8B store
                    int win = mb / VN, mt = mb - win * VN;
                    ushort4 o;
                    o.x = f2bf(acc[i][j][0] + bv);
                    o.y = f2bf(acc[i][j][1] + bv);
                    o.z = f2bf(acc[i][j][2] + bv);
                    o.w = f2bf(acc[i][j][3] + bv);
                    *(ushort4*)(vout + (size_t)((win * HEADS + head) * 64 + dd) * VNP + mt) = o;
                } else {
#pragma unroll
                    for (int r = 0; r < 4; r++) {
                        int m = mb + r;
                        if (m >= M) continue;
                        int win = m / VN, mt = m - win * VN;
                        vout[(size_t)((win * HEADS + head) * 64 + dd) * VNP + mt] =
                            f2bf(acc[i][j][r] + bv);
                    }
                }
                continue;
            }
#pragma unroll
            for (int r = 0; r < 4; r++) {
                int m = mb + r;
                if (m >= M) continue;
                float v = acc[i][j][r] + bv;
                if (OMODE == 0) {
                    ((float*)Cout)[(size_t)m * N + n] = v;
                } else if (OMODE == 2) {
                    v = 0.5f * v * (1.f + erff(v * 0.70710678118654752f));
                    ((unsigned short*)Cout)[(size_t)m * N + n] = f2bf(v);
                } else {  // OMODE 3, n < 1536
                    ((unsigned short*)Cout)[(size_t)m * 2304 + n] = f2bf(v);
                }
            }
        }
    }
}

// ---------------- fused reduce + bias + residual + LayerNorm ---------------
// One block per global row p (1024 rows, 256 thr, 3 elems/thr, C=768).
// h = sum_z part[z][tp] + bias + (extra? extra[p]) + (addH? H[p]); if S>0 H[p]=h.
// LN(h) -> lnout: lnmode 1 straight bf16 [p]; 2 windowed bf16 [win(p)]; 3 raw bf16(h) [p]
template<int S>
__global__ __launch_bounds__(256) void fuse_ln(
        const float* __restrict__ part, size_t pstride, int partwin,
        const float* __restrict__ extra, const float* __restrict__ bias,
        float* __restrict__ H, int addH,
        const float* __restrict__ lnw, const float* __restrict__ lnb,
        unsigned short* __restrict__ lnout, int lnmode) {
    const int p = blockIdx.x;
    const int tw = winidx(p);
    const int tp = partwin ? tw : p;
    const int c0 = threadIdx.x;
    float h[3];
    float s1 = 0.f, s2 = 0.f;
#pragma unroll
    for (int j = 0; j < 3; j++) {
        int c = c0 + j * 256;
        float v = 0.f;
        if (S > 0) {
            v = part[(size_t)tp * EMBED + c];
#pragma unroll
            for (int z = 1; z < S; z++) v += part[(size_t)z * pstride + (size_t)tp * EMBED + c];
            v += bias[c];
        }
        if (extra) v += extra[(size_t)p * EMBED + c];
        if (addH)  v += H[(size_t)p * EMBED + c];
        h[j] = v;
        if (S > 0) H[(size_t)p * EMBED + c] = v;
        s1 += v; s2 += v * v;
    }
    for (int off = 32; off; off >>= 1) {
        s1 += __shfl_down(s1, off);
        s2 += __shfl_down(s2, off);
    }
    __shared__ float sh1[4], sh2[4];
    __shared__ float smu, srstd;
    int wv = threadIdx.x >> 6, ln = threadIdx.x & 63;
    if (ln == 0) { sh1[wv] = s1; sh2[wv] = s2; }
    __syncthreads();
    if (threadIdx.x == 0) {
        float t1 = sh1[0] + sh1[1] + sh1[2] + sh1[3];
        float t2 = sh2[0] + sh2[1] + sh2[2] + sh2[3];
        float m = t1 / (float)EMBED;
        smu = m; srstd = rsqrtf(t2 / (float)EMBED - m * m + LNEPS);
    }
    __syncthreads();
    float m = smu, r = srstd;
    unsigned short* dst = lnout + (size_t)(lnmode == 2 ? tw : p) * EMBED;
#pragma unroll
    for (int j = 0; j < 3; j++) {
        int c = c0 + j * 256;
        float v = (lnmode == 3) ? h[j] : (h[j] - m) * r * lnw[c] + lnb[c];
        dst[c] = f2bf(v);
    }
}

// ---------------- fused neck reduce + LayerNorm (C=256) --------------------
// mode 0: f32 out [M,C]; mode 1: f32 out transposed [C,M]
template<int S>
__global__ __launch_bounds__(256) void fuse_ln_neck(
        const float* __restrict__ part, const float* __restrict__ w,
        const float* __restrict__ b, float* __restrict__ out, int M, int mode) {
    const int row = blockIdx.x, c = threadIdx.x;
    float v = part[(size_t)row * OUTC + c];
#pragma unroll
    for (int z = 1; z < S; z++)
        v += part[(size_t)z * M * OUTC + (size_t)row * OUTC + c];
    float s1 = v, s2 = v * v;
    for (int off = 32; off; off >>= 1) {
        s1 += __shfl_down(s1, off);
        s2 += __shfl_down(s2, off);
    }
    __shared__ float sh1[4], sh2[4];
    __shared__ float smu, srs;
    int wv = threadIdx.x >> 6, ln = threadIdx.x & 63;
    if (ln == 0) { sh1[wv] = s1; sh2[wv] = s2; }
    __syncthreads();
    if (threadIdx.x == 0) {
        float t1 = sh1[0] + sh1[1] + sh1[2] + sh1[3];
        float t2 = sh2[0] + sh2[1] + sh2[2] + sh2[3];
        float m = t1 / (float)OUTC;
        smu = m; srs = rsqrtf(t2 / (float)OUTC - m * m + LNEPS);
    }
    __syncthreads();
    float res = (v - smu) * srs * w[c] + b[c];
    if (mode == 0) out[(size_t)row * OUTC + c] = res;
    else           out[(size_t)c * M + row] = res;
}

// ---------------- fused MFMA flash attention -------------------------------
template<int N, int HH, int WW, int VNP>
__global__ __launch_bounds__(256) void attn_mfma(
        const unsigned short* __restrict__ qkv, const unsigned short* __restrict__ vt,
        const float* __restrict__ rel_h, const float* __restrict__ rel_w,
        unsigned short* __restrict__ out) {
    constexpr int NT = (N + 63) / 64;
    constexpr int JH = ((2 * HH - 1 + 15) / 16) * 16;
    constexpr int JW = ((2 * WW - 1 + 15) / 16) * 16;
    __shared__ unsigned short Pw[4][16 * 72];
    __shared__ float Dh[4][16][JH];
    __shared__ float Dw[4][16][JW];
    const int tid = threadIdx.x, lane = tid & 63, w = tid >> 6;
    const int l15 = lane & 15, q4 = lane >> 4;
    const int bh = blockIdx.y, winI = bh / HEADS, head = bh % HEADS;
    const int base = winI * N;
    const int q0 = blockIdx.x * 64;

    short8 aq0, aq1;
    {
        int qr = q0 + w * 16 + l15; if (qr >= N) qr = N - 1;
        const unsigned short* qp = qkv + (size_t)(base + qr) * 2304 + head * 64;
        aq0 = *(const short8*)(qp + q4 * 8);
        aq1 = *(const short8*)(qp + 32 + q4 * 8);
    }

#pragma unroll
    for (int s = 0; s < JH / 16; s++) {
        int j = s * 16 + l15; if (j > 2 * HH - 2) j = 2 * HH - 2;
        const float* rp = rel_h + (size_t)j * 64 + q4 * 8;
        float4 r0 = *(const float4*)rp;
        float4 r1 = *(const float4*)(rp + 4);
        float4 r2 = *(const float4*)(rp + 32);
        float4 r3 = *(const float4*)(rp + 36);
        short8 b0 = pk8(r0, r1), b1 = pk8(r2, r3);
        float4v df = (float4v){0.f, 0.f, 0.f, 0.f};
        df = __builtin_amdgcn_mfma_f32_16x16x32_bf16(aq0, b0, df, 0, 0, 0);
        df = __builtin_amdgcn_mfma_f32_16x16x32_bf16(aq1, b1, df, 0, 0, 0);
#pragma unroll
        for (int r = 0; r < 4; r++) Dh[w][q4 * 4 + r][s * 16 + l15] = df[r];
    }
#pragma unroll
    for (int s = 0; s < JW / 16; s++) {
        int j = s * 16 + l15; if (j > 2 * WW - 2) j = 2 * WW - 2;
        const float* rp = rel_w + (size_t)j * 64 + q4 * 8;
        float4 r0 = *(const float4*)rp;
        float4 r1 = *(const float4*)(rp + 4);
        float4 r2 = *(const float4*)(rp + 32);
        float4 r3 = *(const float4*)(rp + 36);
        short8 b0 = pk8(r0, r1), b1 = pk8(r2, r3);
        float4v df = (float4v){0.f, 0.f, 0.f, 0.f};
        df = __builtin_amdgcn_mfma_f32_16x16x32_bf16(aq0, b0, df, 0, 0, 0);
        df = __builtin_amdgcn_mfma_f32_16x16x32_bf16(aq1, b1, df, 0, 0, 0);
#pragma unroll
        for (int r = 0; r < 4; r++) Dw[w][q4 * 4 + r][s * 16 + l15] = df[r];
    }

    int qhv[4], qwv[4];
#pragma unroll
    for (int r = 0; r < 4; r++) {
        int qg = q0 + w * 16 + q4 * 4 + r;
        qhv[r] = qg / WW;
        qwv[r] = qg - qhv[r] * WW;
    }

    float m_r[4], l_r[4];
    float4v acc_o[4];
#pragma unroll
    for (int r = 0; r < 4; r++) { m_r[r] = -1e30f; l_r[r] = 0.f; }
#pragma unroll
    for (int s = 0; s < 4; s++) acc_o[s] = (float4v){0.f, 0.f, 0.f, 0.f};

    const unsigned short* vbase = vt + (size_t)bh * 64 * VNP;
    const unsigned short* kqbase = qkv + (size_t)base * 2304 + 768 + head * 64;

    short8 kc[8];
#pragma unroll
    for (int s = 0; s < 4; s++) {
        int kr = s * 16 + l15; if (kr >= N) kr = N - 1;
        const unsigned short* kp = kqbase + (size_t)kr * 2304;
        kc[2 * s]     = *(const short8*)(kp + q4 * 8);
        kc[2 * s + 1] = *(const short8*)(kp + 32 + q4 * 8);
    }

    for (int kt = 0; kt < NT; kt++) {
        short8 vv[8];
        {
            const unsigned short* vb = vbase + kt * 64;
#pragma unroll
            for (int s2 = 0; s2 < 4; s2++) {
                const unsigned short* vr = vb + (size_t)(s2 * 16 + l15) * VNP;
                vv[2 * s2]     = *(const short8*)(vr + q4 * 8);
                vv[2 * s2 + 1] = *(const short8*)(vr + 32 + q4 * 8);
            }
        }
        short8 kn[8];
        {
            int ktn = (kt + 1 < NT) ? kt + 1 : kt;
#pragma unroll
            for (int s = 0; s < 4; s++) {
                int kr = ktn * 64 + s * 16 + l15; if (kr >= N) kr = N - 1;
                const unsigned short* kp = kqbase + (size_t)kr * 2304;
                kn[2 * s]     = *(const short8*)(kp + q4 * 8);
                kn[2 * s + 1] = *(const short8*)(kp + 32 + q4 * 8);
            }
        }
        float sv[4][4];
#pragma unroll
        for (int s = 0; s < 4; s++) {
            float4v sf = (float4v){0.f, 0.f, 0.f, 0.f};
            sf = __builtin_amdgcn_mfma_f32_16x16x32_bf16(aq0, kc[2 * s], sf, 0, 0, 0);
            sf = __builtin_amdgcn_mfma_f32_16x16x32_bf16(aq1, kc[2 * s + 1], sf, 0, 0, 0);
            int col = kt * 64 + s * 16 + l15;
            if (col < N) {
                int kh = col / WW, kw = col - kh * WW;
#pragma unroll
                for (int r = 0; r < 4; r++)
                    sv[s][r] = sf[r] * 0.125f
                             + Dh[w][q4 * 4 + r][qhv[r] - kh + HH - 1]
                             + Dw[w][q4 * 4 + r][qwv[r] - kw + WW - 1];
            } else {
#pragma unroll
                for (int r = 0; r < 4; r++) sv[s][r] = -1e30f;
            }
        }
        float p[4][4];
#pragma unroll
        for (int r = 0; r < 4; r++) {
            float t = fmaxf(fmaxf(sv[0][r], sv[1][r]), fmaxf(sv[2][r], sv[3][r]));
#pragma unroll
            for (int off = 1; off < 16; off <<= 1) t = fmaxf(t, __shfl_xor(t, off));
            float mn = fmaxf(m_r[r], t);
            float alpha = __expf(m_r[r] - mn);
            m_r[r] = mn;
            float ps = 0.f;
#pragma unroll
            for (int s = 0; s < 4; s++) { p[s][r] = __expf(sv[s][r] - mn); ps += p[s][r]; }
#pragma unroll
            for (int off = 1; off < 16; off <<= 1) ps += __shfl_xor(ps, off);
            l_r[r] = l_r[r] * alpha + ps;
#pragma unroll
            for (int s = 0; s < 4; s++) acc_o[s][r] *= alpha;
        }
#pragma unroll
        for (int s = 0; s < 4; s++)
#pragma unroll
            for (int r = 0; r < 4; r++)
                Pw[w][(q4 * 4 + r) * 72 + s * 16 + l15] = f2bf(p[s][r]);
        short8 af0 = *(const short8*)(&Pw[w][l15 * 72 + q4 * 8]);
        short8 af1 = *(const short8*)(&Pw[w][l15 * 72 + 32 + q4 * 8]);
#pragma unroll
        for (int s2 = 0; s2 < 4; s2++) {
            acc_o[s2] = __builtin_amdgcn_mfma_f32_16x16x32_bf16(af0, vv[2 * s2], acc_o[s2], 0, 0, 0);
            acc_o[s2] = __builtin_amdgcn_mfma_f32_16x16x32_bf16(af1, vv[2 * s2 + 1], acc_o[s2], 0, 0, 0);
        }
#pragma unroll
        for (int i = 0; i < 8; i++) kc[i] = kn[i];
    }
#pragma unroll
    for (int r = 0; r < 4; r++) {
        int qg = q0 + w * 16 + q4 * 4 + r;
        if (qg >= N) continue;
        float inv = 1.f / l_r[r];
#pragma unroll
        for (int s2 = 0; s2 < 4; s2++)
            out[(size_t)(base + qg) * EMBED + head * 64 + s2 * 16 + l15] =
                f2bf(acc_o[s2][r] * inv);
    }
}

// ---------------- patch-embed im2col (bf16 out) ----------------------------
__global__ void im2col_patch(const float* __restrict__ x, unsigned short* __restrict__ A, int n) {
    int i = blockIdx.x * blockDim.x + threadIdx.x;
    if (i >= n) return;
    int t = i / EMBED, kidx = i % EMBED;
    int c = kidx >> 8, r = kidx & 255;
    int ph = r >> 4, pw = r & 15;
    int ty = t >> 5, tx = t & 31;
    A[i] = f2bf(x[(size_t)c * 512 * 512 + (size_t)(ty * 16 + ph) * 512 + (tx * 16 + pw)]);
}

// ---------------- neck 3x3 conv im2col (bf16 out) --------------------------
__global__ void im2col3(const float* __restrict__ in, unsigned short* __restrict__ out, int n) {
    int i = blockIdx.x * blockDim.x + threadIdx.x;
    if (i >= n) return;
    int p = i / 2304, k = i % 2304;
    int c = k / 9, r9 = k % 9;
    int ky = r9 / 3, kx = r9 % 3;
    int py = p >> 5, px = p & 31;
    int ny = py + ky - 1, nx = px + kx - 1;
    float v = (ny >= 0 && ny < TOKS && nx >= 0 && nx < TOKS)
                ? in[(size_t)(ny * TOKS + nx) * OUTC + c] : 0.f;
    out[i] = f2bf(v);
}

// ---------------- host orchestration ---------------------------------------
extern "C" void kernel_launch(void* const* d_in, const int* in_sizes, int n_in,
                              void* d_out, int out_size, void* d_ws, size_t ws_size,
                              hipStream_t stream) {
    const float* x        = (const float*)d_in[0];
    const float* patch_w  = (const float*)d_in[1];
    const float* patch_b  = (const float*)d_in[2];
    const float* pos      = (const float*)d_in[3];
    const float* qkv_w    = (const float*)d_in[4];
    const float* qkv_b    = (const float*)d_in[5];
    const float* proj_w   = (const float*)d_in[6];
    const float* proj_b   = (const float*)d_in[7];
    const float* n1w      = (const float*)d_in[8];
    const float* n1b      = (const float*)d_in[9];
    const float* n2w      = (const float*)d_in[10];
    const float* n2b      = (const float*)d_in[11];
    const float* mlp_w1   = (const float*)d_in[12];
    const float* mlp_b1   = (const float*)d_in[13];
    const float* mlp_w2   = (const float*)d_in[14];
    const float* mlp_b2   = (const float*)d_in[15];
    const float* rhw      = (const float*)d_in[16];
    const float* rww      = (const float*)d_in[17];
    const float* rhg      = (const float*)d_in[18];
    const float* rwg      = (const float*)d_in[19];
    const float* neck_w1  = (const float*)d_in[20];
    const float* nl1w     = (const float*)d_in[21];
    const float* nl1b     = (const float*)d_in[22];
    const float* neck_w2  = (const float*)d_in[23];
    const float* nl2w     = (const float*)d_in[24];
    const float* nl2b     = (const float*)d_in[25];

    const size_t SZ_QKVW = (size_t)2304 * 768;
    const size_t SZ_PROJ = (size_t)768 * 768;
    const size_t SZ_MLP1 = (size_t)3072 * 768;
    const size_t SZ_MLP2 = (size_t)768 * 3072;

    char* p = (char*)d_ws;
    float* H    = (float*)p;            p += (size_t)NTOK * EMBED * 4;
    unsigned short* QKVb = (unsigned short*)p; p += (size_t)WTOK * 2304 * 2;
    unsigned short* Vt   = (unsigned short*)p; p += (size_t)NWIN * HEADS * 64 * 208 * 2 + 4096;
    float* LNF  = (float*)p;            p += (size_t)NTOK * OUTC * 4;
    unsigned short* XWw = (unsigned short*)p;  p += (size_t)WTOK * EMBED * 2;
    unsigned short* XWs = (unsigned short*)p;  p += (size_t)NTOK * EMBED * 2;
    unsigned short* AOb = (unsigned short*)p;  p += (size_t)WTOK * EMBED * 2;
    float* SPK  = (float*)p;            p += (size_t)16 * 1024 * 1024;
    unsigned short* PWb  = (unsigned short*)p; p += SZ_PROJ * 2;
    unsigned short* NW1b = (unsigned short*)p; p += (size_t)OUTC * 768 * 2;
    unsigned short* NW2b = (unsigned short*)p; p += (size_t)OUTC * 2304 * 2;
    unsigned short* MIDB  = QKVb;   // alias: MLP mid 1024x3072 bf16
    unsigned short* CONVA = QKVb;   // alias: neck im2col 1024x2304 bf16

    // all-layer preconverted weights (if workspace allows)
    unsigned short* WQa = (unsigned short*)p;
    size_t needAll = (size_t)(p - (char*)d_ws) +
                     (SZ_QKVW + SZ_PROJ + SZ_MLP1 + SZ_MLP2) * 2 * DEPTH;
    bool pre = ws_size >= needAll;
    unsigned short *WPa, *W1a, *W2a;
    size_t sQ, sP, s1, s2;
    if (pre) {
        WPa = WQa + SZ_QKVW * DEPTH;
        W1a = WPa + SZ_PROJ * DEPTH;
        W2a = W1a + SZ_MLP1 * DEPTH;
        sQ = SZ_QKVW; sP = SZ_PROJ; s1 = SZ_MLP1; s2 = SZ_MLP2;
    } else {
        WPa = WQa + SZ_QKVW;
        W1a = WPa + SZ_PROJ;
        W2a = W1a + SZ_MLP1;
        sQ = sP = s1 = s2 = 0;
    }

    const int NE = NTOK * EMBED;

    zero_pads<<<WTOK, 256, 0, stream>>>(XWw);
    if (pre) {
        convw_all<<<84288, 256, 0, stream>>>(
            qkv_w, proj_w, mlp_w1, mlp_w2, patch_w, neck_w1, neck_w2,
            WQa, WPa, W1a, W2a, PWb, NW1b, NW2b);
    } else {
        f2b4<<<(EMBED * EMBED / 4 + 255) / 256, 256, 0, stream>>>(patch_w, PWb, EMBED * EMBED / 4);
        f2b4<<<(OUTC * EMBED / 4 + 255) / 256, 256, 0, stream>>>(neck_w1, NW1b, OUTC * EMBED / 4);
        f2b4<<<(OUTC * 2304 / 4 + 255) / 256, 256, 0, stream>>>(neck_w2, NW2b, OUTC * 2304 / 4);
    }

    // ---- patch embed (split-K=2) + fused [sum + patch_b + pos -> H; LN1 -> windowed] ----
    im2col_patch<<<(NE + 255) / 256, 256, 0, stream>>>(x, AOb, NE);
    gemm_rd<0, 2, 6><<<dim3(EMBED / 64, NTOK / 64, 2), 256, 0, stream>>>(
        AOb, PWb, nullptr, SPK, NTOK, EMBED, EMBED, nullptr, 0, 0);
    fuse_ln<2><<<NTOK, 256, 0, stream>>>(
        SPK, (size_t)NTOK * EMBED, 0, pos, patch_b, H, 0, n1w, n1b, XWw, 2);

    for (int i = 0; i < DEPTH; i++) {
        bool glob = (i == 2 || i == 5 || i == 8 || i == 11);
        const unsigned short* wq = WQa + sQ * i;
        const unsigned short* wp = WPa + sP * i;
        const unsigned short* w1 = W1a + s1 * i;
        const unsigned short* w2 = W2a + s2 * i;
        if (!pre)
            convw4<<<(1769472 + 255) / 256, 256, 0, stream>>>(
                qkv_w + (size_t)i * SZ_QKVW, proj_w + (size_t)i * SZ_PROJ,
                mlp_w1 + (size_t)i * SZ_MLP1, mlp_w2 + (size_t)i * SZ_MLP2,
                WQa, WPa, W1a, W2a);

        if (!glob) {
            gemm_rd<3, 1, 12><<<dim3(2304 / 64, (WTOK + 63) / 64), 256, 0, stream>>>(
                XWw, wq, qkv_b + i * 2304, QKVb, WTOK, 2304, EMBED, Vt, WN, 208);
            attn_mfma<WN, WINSZ, WINSZ, 208><<<dim3(4, NWIN * HEADS), 256, 0, stream>>>(
                QKVb, Vt, rhw + (size_t)i * 27 * 64, rww + (size_t)i * 27 * 64, AOb);
            gemm_rd<0, 2, 6><<<dim3(EMBED / 64, (WTOK + 63) / 64, 2), 256, 0, stream>>>(
                AOb, wp, nullptr, SPK, WTOK, EMBED, EMBED, nullptr, 0, 0);
            fuse_ln<2><<<NTOK, 256, 0, stream>>>(
                SPK, (size_t)WTOK * EMBED, 1, nullptr, proj_b + i * EMBED, H, 1,
                n2w + i * EMBED, n2b + i * EMBED, XWs, 1);
        } else {
            gemm_rd<3, 1, 12><<<dim3(2304 / 64, NTOK / 64), 256, 0, stream>>>(
                XWs, wq, qkv_b + i * 2304, QKVb, NTOK, 2304, EMBED, Vt, NTOK, NTOK);
            attn_mfma<NTOK, TOKS, TOKS, NTOK><<<dim3(16, HEADS), 256, 0, stream>>>(
                QKVb, Vt, rhg + (size_t)i * 63 * 64, rwg + (size_t)i * 63 * 64, AOb);
            gemm_rd<0, 2, 6><<<dim3(EMBED / 64, NTOK / 64, 2), 256, 0, stream>>>(
                AOb, wp, nullptr, SPK, NTOK, EMBED, EMBED, nullptr, 0, 0);
            fuse_ln<2><<<NTOK, 256, 0, stream>>>(
                SPK, (size_t)NTOK * EMBED, 0, nullptr, proj_b + i * EMBED, H, 1,
                n2w + i * EMBED, n2b + i * EMBED, XWs, 1);
        }
        // MLP
        gemm_rd<2, 1, 12><<<dim3(MLPDIM / 64, NTOK / 64), 256, 0, stream>>>(
            XWs, w1, mlp_b1 + i * MLPDIM, MIDB, NTOK, MLPDIM, EMBED, nullptr, 0, 0);
        gemm_rd<0, 4, 12><<<dim3(EMBED / 64, NTOK / 64, 4), 256, 0, stream>>>(
            MIDB, w2, nullptr, SPK, NTOK, EMBED, MLPDIM, nullptr, 0, 0);
        int nlnmode; const float* nw; const float* nb; unsigned short* ndst;
        if (i == DEPTH - 1) { nlnmode = 3; nw = n1w; nb = n1b; ndst = XWs; }
        else {
            bool nglob = (i + 1 == 2 || i + 1 == 5 || i + 1 == 8 || i + 1 == 11);
            nlnmode = nglob ? 1 : 2;
            nw = n1w + (size_t)(i + 1) * EMBED; nb = n1b + (size_t)(i + 1) * EMBED;
            ndst = nglob ? XWs : XWw;
        }
        fuse_ln<4><<<NTOK, 256, 0, stream>>>(
            SPK, (size_t)NTOK * EMBED, 0, nullptr, mlp_b2 + i * EMBED, H, 1,
            nw, nb, ndst, nlnmode);
    }

    // ---- neck ----
    gemm_rd<0, 4, 3><<<dim3(OUTC / 64, NTOK / 64, 4), 256, 0, stream>>>(
        XWs, NW1b, nullptr, SPK, NTOK, OUTC, EMBED, nullptr, 0, 0);
    fuse_ln_neck<4><<<NTOK, 256, 0, stream>>>(SPK, nl1w, nl1b, LNF, NTOK, 0);
    im2col3<<<(NTOK * 2304 + 255) / 256, 256, 0, stream>>>(LNF, CONVA, NTOK * 2304);
    gemm_rd<0, 6, 6><<<dim3(OUTC / 64, NTOK / 64, 6), 256, 0, stream>>>(
        CONVA, NW2b, nullptr, SPK, NTOK, OUTC, 2304, nullptr, 0, 0);
    fuse_ln_neck<6><<<NTOK, 256, 0, stream>>>(SPK, nl2w, nl2b, (float*)d_out, NTOK, 1);
}

// Round 9
// 1763.090 us; speedup vs baseline: 1.4433x; 1.3962x over previous
//
#include <hip/hip_runtime.h>
#include <math.h>

#define EMBED   768
#define HEADS   12
#define DEPTH   12
#define TOKS    32
#define NTOK    1024
#define WINSZ   14
#define NWIN    9
#define WTOK    1764        // 9*196
#define WN      196
#define MLPDIM  3072
#define OUTC    256
#define LNEPS   1e-6f

typedef __attribute__((ext_vector_type(8))) short short8;
typedef __attribute__((ext_vector_type(4))) float float4v;

__device__ __forceinline__ unsigned short f2bf(float f) {
    unsigned u = __float_as_uint(f);
    unsigned r = (u + 0x7fffu + ((u >> 16) & 1u)) >> 16;
    return (unsigned short)r;
}
__device__ __forceinline__ float bf2f(unsigned short s) {
    return __uint_as_float((unsigned)s << 16);
}
// packed f32->bf16 (RNE, identical to f2bf)
__device__ __forceinline__ unsigned cvtpk(float a, float b) {
    unsigned r;
    asm("v_cvt_pk_bf16_f32 %0, %1, %2" : "=v"(r) : "v"(a), "v"(b));
    return r;
}
__device__ __forceinline__ short8 pk8(float4 a, float4 b) {
    union { unsigned u[4]; short8 s; } t;
    t.u[0] = cvtpk(a.x, a.y); t.u[1] = cvtpk(a.z, a.w);
    t.u[2] = cvtpk(b.x, b.y); t.u[3] = cvtpk(b.z, b.w);
    return t.s;
}
// global row p (0..1023) -> window-token index
__device__ __forceinline__ int winidx(int p) {
    int gy = p >> 5, gx = p & 31;
    return ((gy / WINSZ) * 3 + gx / WINSZ) * WN + (gy % WINSZ) * WINSZ + (gx % WINSZ);
}

// =================== fragment-tiled layout ==================================
// T'[(row/16)(col/8)(row%16)][8]: elem off = ((rb*(K/8)+kc)*16 + rl)*8 + (c&7)
// A wave's MFMA fragment load (lane = q4*16+l15) becomes ONE contiguous 1KB
// access: base + q4*128 + l15*8. This removes the 16-line-per-load scatter
// of row-major fragment loads (rows K*2 bytes apart) -> VMEM transaction
// count per K-tile drops ~16x (the measured bottleneck).

// whole-model weight conversion f32 -> tiled bf16, ONE launch.
// Output is written perfectly linearly (chunk g -> out[g*8..g*8+7]).
// Chunk totals (8-elem units): qkv 2654208 | proj 884736 | mlp1 3538944 |
// mlp2 3538944 | patch 73728 | neck1 24576 | neck2 73728  = 10788864.
// All boundaries are multiples of 256 -> block-uniform select.
__global__ __launch_bounds__(256) void convw_all(
        const float* __restrict__ q,  const float* __restrict__ pr,
        const float* __restrict__ m1, const float* __restrict__ m2,
        const float* __restrict__ pw, const float* __restrict__ n1,
        const float* __restrict__ n2,
        unsigned short* __restrict__ oq,  unsigned short* __restrict__ opr,
        unsigned short* __restrict__ om1, unsigned short* __restrict__ om2,
        unsigned short* __restrict__ opw, unsigned short* __restrict__ on1,
        unsigned short* __restrict__ on2) {
    int g = blockIdx.x * 256 + threadIdx.x;
    const float* s; unsigned short* o; int off; int K;
    if (g < 2654208)        { s = q;  o = oq;  off = g;            K = 768;  }
    else if (g < 3538944)   { s = pr; o = opr; off = g - 2654208;  K = 768;  }
    else if (g < 7077888)   { s = m1; o = om1; off = g - 3538944;  K = 768;  }
    else if (g < 10616832)  { s = m2; o = om2; off = g - 7077888;  K = 3072; }
    else if (g < 10690560)  { s = pw; o = opw; off = g - 10616832; K = 768;  }
    else if (g < 10715136)  { s = n1; o = on1; off = g - 10690560; K = 768;  }
    else                    { s = n2; o = on2; off = g - 10715136; K = 2304; }
    int twoK = 2 * K;
    int rb = off / twoK, rem = off - rb * twoK;
    int kc = rem >> 4, rl = rem & 15;
    const float* sp = s + (size_t)(rb * 16 + rl) * K + kc * 8;
    float4 v0 = *(const float4*)sp, v1 = *(const float4*)(sp + 4);
    *(short8*)(o + (size_t)off * 8) = pk8(v0, v1);
}

// single-tensor tiled conversion (fallback path), grid-stride free
__global__ __launch_bounds__(256) void convw_one(
        const float* __restrict__ in, unsigned short* __restrict__ out,
        int K, int nchunk) {
    int g = blockIdx.x * 256 + threadIdx.x;
    if (g >= nchunk) return;
    int twoK = 2 * K;
    int rb = g / twoK, rem = g - rb * twoK;
    int kc = rem >> 4, rl = rem & 15;
    const float* sp = in + (size_t)(rb * 16 + rl) * K + kc * 8;
    float4 v0 = *(const float4*)sp, v1 = *(const float4*)(sp + 4);
    *(short8*)(out + (size_t)g * 8) = pk8(v0, v1);
}

// zero the pad rows of the windowed LN buffer (tiled layout, once)
__global__ __launch_bounds__(256) void zero_pads(unsigned short* __restrict__ XWw) {
    int t = blockIdx.x;                    // 0..1763
    int w = t / WN, r = t % WN;
    int gy = (w / 3) * WINSZ + r / WINSZ, gx = (w % 3) * WINSZ + r % WINSZ;
    if (gy < TOKS && gx < TOKS) return;
    unsigned short* dst = XWw + (size_t)(t >> 4) * 12288 + (size_t)(t & 15) * 8;
    for (int c = threadIdx.x; c < EMBED; c += 256)
        dst[(size_t)(c >> 3) * 128 + (c & 7)] = 0;
}

// ---------------- register-direct MFMA GEMM, tiled operands ----------------
// C[M,N] = A[M,K] @ B[N,K]^T + bias. Barrier-free, LDS-free; 4 waves; block
// tile 64x64 (wave 32x32); 3-slot rolling prefetch; XCD-bijective swizzle.
// B is ALWAYS fragment-tiled (weights). A tiled iff AT==1 (XWw/XWs inputs);
// AT==0 reads row-major with clamp (im2col / gemm-produced activations).
// OMODE: 0 = f32 out, 2 = bf16+GELU out, 3 = qkv split (bf16 Q/K + transp V)
// SPLIT>1: grid.z splits K; partial f32 written to Cout + z*M*N (no bias).
#define LDT(S, KO) do {                                               \
    _Pragma("unroll")                                                 \
    for (int i_ = 0; i_ < 2; i_++) {                                  \
        a_##S[i_][0] = *(const short8*)(ap[i_] + (size_t)(KO) * AKS); \
        a_##S[i_][1] = *(const short8*)(ap[i_] + (size_t)(KO) * AKS + 32 * AKS); } \
    _Pragma("unroll")                                                 \
    for (int j_ = 0; j_ < 2; j_++) {                                  \
        b_##S[j_][0] = *(const short8*)(bp[j_] + (size_t)(KO) * 16);  \
        b_##S[j_][1] = *(const short8*)(bp[j_] + (size_t)(KO) * 16 + 512); } \
} while (0)

#define MFMA_SLOT(S) do {                                       \
    _Pragma("unroll")                                           \
    for (int h_ = 0; h_ < 2; h_++)                              \
        _Pragma("unroll")                                       \
        for (int i_ = 0; i_ < 2; i_++)                          \
            _Pragma("unroll")                                   \
            for (int j_ = 0; j_ < 2; j_++)                      \
                acc[i_][j_] = __builtin_amdgcn_mfma_f32_16x16x32_bf16( \
                    a_##S[i_][h_], b_##S[j_][h_], acc[i_][j_], 0, 0, 0); \
} while (0)

template<int OMODE, int SPLIT, int NT, int AT>
__global__ __launch_bounds__(256) void gemm_rd(
        const unsigned short* __restrict__ A, const unsigned short* __restrict__ B,
        const float* __restrict__ bias, void* __restrict__ Cout,
        int M, int N, int K,
        unsigned short* __restrict__ vout, int VN, int VNP) {
    const int tid = threadIdx.x, lane = tid & 63, wave = tid >> 6;
    const int wm = wave >> 1, wn = wave & 1;
    const int l15 = lane & 15, q4 = lane >> 4;
    const int AKS = AT ? 16 : 1;

    // ---- XCD-aware bijective swizzle (m204), m-fastest decode ----
    const int gx = gridDim.x, gy = gridDim.y;
    const int nb = gx * gy;
    const int f  = blockIdx.y * gx + blockIdx.x;
    const int qq = nb >> 3, rr = nb & 7;
    const int xcd = f & 7, sl = f >> 3;
    const int wg = (xcd < rr) ? xcd * (qq + 1) + sl
                              : rr * (qq + 1) + (xcd - rr) * qq + sl;
    const int bn = wg / gy;
    const int bm = wg - bn * gy;

    const int m0 = bm * 64 + wm * 32;
    const int n0 = bn * 64 + wn * 32;
    const int kb = blockIdx.z * (NT * 64);
    const int Kc8 = K >> 3;

    const unsigned short* ap[2];
    if (AT) {
#pragma unroll
        for (int i = 0; i < 2; i++) {
            int mb = (m0 + i * 16) >> 4;
            ap[i] = A + ((size_t)mb * Kc8 + (kb >> 3)) * 128 + q4 * 128 + l15 * 8;
        }
    } else {
#pragma unroll
        for (int i = 0; i < 2; i++) {
            int gm = m0 + i * 16 + l15; if (gm >= M) gm = M - 1;
            ap[i] = A + (size_t)gm * K + kb + q4 * 8;
        }
    }
    const unsigned short* bp[2];
#pragma unroll
    for (int j = 0; j < 2; j++) {
        int nb2 = (n0 + j * 16) >> 4;
        bp[j] = B + ((size_t)nb2 * Kc8 + (kb >> 3)) * 128 + q4 * 128 + l15 * 8;
    }

    float4v acc[2][2];
#pragma unroll
    for (int i = 0; i < 2; i++)
#pragma unroll
        for (int j = 0; j < 2; j++) acc[i][j] = (float4v){0.f, 0.f, 0.f, 0.f};

    short8 a_0[2][2], b_0[2][2];
    short8 a_1[2][2], b_1[2][2];
    short8 a_2[2][2], b_2[2][2];

    LDT(0, 0);
    LDT(1, 64);
#pragma unroll
    for (int k = 0; k + 3 < NT; k += 3) {
        LDT(2, (k + 2) * 64); MFMA_SLOT(0);
        LDT(0, (k + 3) * 64); MFMA_SLOT(1);
        LDT(1, (k + 4) * 64); MFMA_SLOT(2);
    }
    LDT(2, (NT - 1) * 64);
    MFMA_SLOT(0); MFMA_SLOT(1); MFMA_SLOT(2);

    if (SPLIT > 1) {
        float* P = (float*)Cout + (size_t)blockIdx.z * M * N;
#pragma unroll
        for (int i = 0; i < 2; i++)
#pragma unroll
            for (int r = 0; r < 4; r++) {
                int m = m0 + i * 16 + q4 * 4 + r;
                if (m >= M) continue;
#pragma unroll
                for (int j = 0; j < 2; j++)
                    P[(size_t)m * N + n0 + j * 16 + l15] = acc[i][j][r];
            }
        return;
    }
#pragma unroll
    for (int i = 0; i < 2; i++) {
        int mb = m0 + i * 16 + q4 * 4;
#pragma unroll
        for (int j = 0; j < 2; j++) {
            int n = n0 + j * 16 + l15;
            float bv = bias ? bias[n] : 0.f;
            if (OMODE == 3 && n >= 1536) {
                int nn = n - 1536;
                int head = nn >> 6, dd = nn & 63;
                if (mb + 3 < M) {
                    int win = mb / VN, mt = mb - win * VN;
                    ushort4 o;
                    o.x = f2bf(acc[i][j][0] + bv);
                    o.y = f2bf(acc[i][j][1] + bv);
                    o.z = f2bf(acc[i][j][2] + bv);
                    o.w = f2bf(acc[i][j][3] + bv);
                    *(ushort4*)(vout + (size_t)((win * HEADS + head) * 64 + dd) * VNP + mt) = o;
                } else {
#pragma unroll
                    for (int r = 0; r < 4; r++) {
                        int m = mb + r;
                        if (m >= M) continue;
                        int win = m / VN, mt = m - win * VN;
                        vout[(size_t)((win * HEADS + head) * 64 + dd) * VNP + mt] =
                            f2bf(acc[i][j][r] + bv);
                    }
                }
                continue;
            }
#pragma unroll
            for (int r = 0; r < 4; r++) {
                int m = mb + r;
                if (m >= M) continue;
                float v = acc[i][j][r] + bv;
                if (OMODE == 0) {
                    ((float*)Cout)[(size_t)m * N + n] = v;
                } else if (OMODE == 2) {
                    v = 0.5f * v * (1.f + erff(v * 0.70710678118654752f));
                    ((unsigned short*)Cout)[(size_t)m * N + n] = f2bf(v);
                } else {  // OMODE 3, n < 1536
                    ((unsigned short*)Cout)[(size_t)m * 2304 + n] = f2bf(v);
                }
            }
        }
    }
}

// ---------------- fused reduce + bias + residual + LayerNorm ---------------
// One block per global row p. LN(h) -> lnout written in FRAGMENT-TILED bf16
// (K=768: 96 chunks, row-block stride 12288): lnmode 1 straight row p;
// 2 windowed row win(p); 3 raw bf16(h) row p.
template<int S>
__global__ __launch_bounds__(256) void fuse_ln(
        const float* __restrict__ part, size_t pstride, int partwin,
        const float* __restrict__ extra, const float* __restrict__ bias,
        float* __restrict__ H, int addH,
        const float* __restrict__ lnw, const float* __restrict__ lnb,
        unsigned short* __restrict__ lnout, int lnmode) {
    const int p = blockIdx.x;
    const int tw = winidx(p);
    const int tp = partwin ? tw : p;
    const int c0 = threadIdx.x;
    float h[3];
    float s1 = 0.f, s2 = 0.f;
#pragma unroll
    for (int j = 0; j < 3; j++) {
        int c = c0 + j * 256;
        float v = 0.f;
        if (S > 0) {
            v = part[(size_t)tp * EMBED + c];
#pragma unroll
            for (int z = 1; z < S; z++) v += part[(size_t)z * pstride + (size_t)tp * EMBED + c];
            v += bias[c];
        }
        if (extra) v += extra[(size_t)p * EMBED + c];
        if (addH)  v += H[(size_t)p * EMBED + c];
        h[j] = v;
        if (S > 0) H[(size_t)p * EMBED + c] = v;
        s1 += v; s2 += v * v;
    }
    for (int off = 32; off; off >>= 1) {
        s1 += __shfl_down(s1, off);
        s2 += __shfl_down(s2, off);
    }
    __shared__ float sh1[4], sh2[4];
    __shared__ float smu, srstd;
    int wv = threadIdx.x >> 6, ln = threadIdx.x & 63;
    if (ln == 0) { sh1[wv] = s1; sh2[wv] = s2; }
    __syncthreads();
    if (threadIdx.x == 0) {
        float t1 = sh1[0] + sh1[1] + sh1[2] + sh1[3];
        float t2 = sh2[0] + sh2[1] + sh2[2] + sh2[3];
        float m = t1 / (float)EMBED;
        smu = m; srstd = rsqrtf(t2 / (float)EMBED - m * m + LNEPS);
    }
    __syncthreads();
    float m = smu, r = srstd;
    int R = (lnmode == 2) ? tw : p;
    unsigned short* dst = lnout + (size_t)(R >> 4) * 12288 + (size_t)(R & 15) * 8;
#pragma unroll
    for (int j = 0; j < 3; j++) {
        int c = c0 + j * 256;
        float v = (lnmode == 3) ? h[j] : (h[j] - m) * r * lnw[c] + lnb[c];
        dst[(size_t)(c >> 3) * 128 + (c & 7)] = f2bf(v);
    }
}

// ---------------- fused neck reduce + LayerNorm (C=256) --------------------
// mode 0: f32 out [M,C]; mode 1: f32 out transposed [C,M]
template<int S>
__global__ __launch_bounds__(256) void fuse_ln_neck(
        const float* __restrict__ part, const float* __restrict__ w,
        const float* __restrict__ b, float* __restrict__ out, int M, int mode) {
    const int row = blockIdx.x, c = threadIdx.x;
    float v = part[(size_t)row * OUTC + c];
#pragma unroll
    for (int z = 1; z < S; z++)
        v += part[(size_t)z * M * OUTC + (size_t)row * OUTC + c];
    float s1 = v, s2 = v * v;
    for (int off = 32; off; off >>= 1) {
        s1 += __shfl_down(s1, off);
        s2 += __shfl_down(s2, off);
    }
    __shared__ float sh1[4], sh2[4];
    __shared__ float smu, srs;
    int wv = threadIdx.x >> 6, ln = threadIdx.x & 63;
    if (ln == 0) { sh1[wv] = s1; sh2[wv] = s2; }
    __syncthreads();
    if (threadIdx.x == 0) {
        float t1 = sh1[0] + sh1[1] + sh1[2] + sh1[3];
        float t2 = sh2[0] + sh2[1] + sh2[2] + sh2[3];
        float m = t1 / (float)OUTC;
        smu = m; srs = rsqrtf(t2 / (float)OUTC - m * m + LNEPS);
    }
    __syncthreads();
    float res = (v - smu) * srs * w[c] + b[c];
    if (mode == 0) out[(size_t)row * OUTC + c] = res;
    else           out[(size_t)c * M + row] = res;
}

// ---------------- fused MFMA flash attention (unchanged) -------------------
template<int N, int HH, int WW, int VNP>
__global__ __launch_bounds__(256) void attn_mfma(
        const unsigned short* __restrict__ qkv, const unsigned short* __restrict__ vt,
        const float* __restrict__ rel_h, const float* __restrict__ rel_w,
        unsigned short* __restrict__ out) {
    constexpr int NT = (N + 63) / 64;
    constexpr int JH = ((2 * HH - 1 + 15) / 16) * 16;
    constexpr int JW = ((2 * WW - 1 + 15) / 16) * 16;
    __shared__ unsigned short Pw[4][16 * 72];
    __shared__ float Dh[4][16][JH];
    __shared__ float Dw[4][16][JW];
    const int tid = threadIdx.x, lane = tid & 63, w = tid >> 6;
    const int l15 = lane & 15, q4 = lane >> 4;
    const int bh = blockIdx.y, winI = bh / HEADS, head = bh % HEADS;
    const int base = winI * N;
    const int q0 = blockIdx.x * 64;

    short8 aq0, aq1;
    {
        int qr = q0 + w * 16 + l15; if (qr >= N) qr = N - 1;
        const unsigned short* qp = qkv + (size_t)(base + qr) * 2304 + head * 64;
        aq0 = *(const short8*)(qp + q4 * 8);
        aq1 = *(const short8*)(qp + 32 + q4 * 8);
    }

#pragma unroll
    for (int s = 0; s < JH / 16; s++) {
        int j = s * 16 + l15; if (j > 2 * HH - 2) j = 2 * HH - 2;
        const float* rp = rel_h + (size_t)j * 64 + q4 * 8;
        float4 r0 = *(const float4*)rp;
        float4 r1 = *(const float4*)(rp + 4);
        float4 r2 = *(const float4*)(rp + 32);
        float4 r3 = *(const float4*)(rp + 36);
        short8 b0 = pk8(r0, r1), b1 = pk8(r2, r3);
        float4v df = (float4v){0.f, 0.f, 0.f, 0.f};
        df = __builtin_amdgcn_mfma_f32_16x16x32_bf16(aq0, b0, df, 0, 0, 0);
        df = __builtin_amdgcn_mfma_f32_16x16x32_bf16(aq1, b1, df, 0, 0, 0);
#pragma unroll
        for (int r = 0; r < 4; r++) Dh[w][q4 * 4 + r][s * 16 + l15] = df[r];
    }
#pragma unroll
    for (int s = 0; s < JW / 16; s++) {
        int j = s * 16 + l15; if (j > 2 * WW - 2) j = 2 * WW - 2;
        const float* rp = rel_w + (size_t)j * 64 + q4 * 8;
        float4 r0 = *(const float4*)rp;
        float4 r1 = *(const float4*)(rp + 4);
        float4 r2 = *(const float4*)(rp + 32);
        float4 r3 = *(const float4*)(rp + 36);
        short8 b0 = pk8(r0, r1), b1 = pk8(r2, r3);
        float4v df = (float4v){0.f, 0.f, 0.f, 0.f};
        df = __builtin_amdgcn_mfma_f32_16x16x32_bf16(aq0, b0, df, 0, 0, 0);
        df = __builtin_amdgcn_mfma_f32_16x16x32_bf16(aq1, b1, df, 0, 0, 0);
#pragma unroll
        for (int r = 0; r < 4; r++) Dw[w][q4 * 4 + r][s * 16 + l15] = df[r];
    }

    int qhv[4], qwv[4];
#pragma unroll
    for (int r = 0; r < 4; r++) {
        int qg = q0 + w * 16 + q4 * 4 + r;
        qhv[r] = qg / WW;
        qwv[r] = qg - qhv[r] * WW;
    }

    float m_r[4], l_r[4];
    float4v acc_o[4];
#pragma unroll
    for (int r = 0; r < 4; r++) { m_r[r] = -1e30f; l_r[r] = 0.f; }
#pragma unroll
    for (int s = 0; s < 4; s++) acc_o[s] = (float4v){0.f, 0.f, 0.f, 0.f};

    const unsigned short* vbase = vt + (size_t)bh * 64 * VNP;
    const unsigned short* kqbase = qkv + (size_t)base * 2304 + 768 + head * 64;

    short8 kc[8];
#pragma unroll
    for (int s = 0; s < 4; s++) {
        int kr = s * 16 + l15; if (kr >= N) kr = N - 1;
        const unsigned short* kp = kqbase + (size_t)kr * 2304;
        kc[2 * s]     = *(const short8*)(kp + q4 * 8);
        kc[2 * s + 1] = *(const short8*)(kp + 32 + q4 * 8);
    }

    for (int kt = 0; kt < NT; kt++) {
        short8 vv[8];
        {
            const unsigned short* vb = vbase + kt * 64;
#pragma unroll
            for (int s2 = 0; s2 < 4; s2++) {
                const unsigned short* vr = vb + (size_t)(s2 * 16 + l15) * VNP;
                vv[2 * s2]     = *(const short8*)(vr + q4 * 8);
                vv[2 * s2 + 1] = *(const short8*)(vr + 32 + q4 * 8);
            }
        }
        short8 kn[8];
        {
            int ktn = (kt + 1 < NT) ? kt + 1 : kt;
#pragma unroll
            for (int s = 0; s < 4; s++) {
                int kr = ktn * 64 + s * 16 + l15; if (kr >= N) kr = N - 1;
                const unsigned short* kp = kqbase + (size_t)kr * 2304;
                kn[2 * s]     = *(const short8*)(kp + q4 * 8);
                kn[2 * s + 1] = *(const short8*)(kp + 32 + q4 * 8);
            }
        }
        float sv[4][4];
#pragma unroll
        for (int s = 0; s < 4; s++) {
            float4v sf = (float4v){0.f, 0.f, 0.f, 0.f};
            sf = __builtin_amdgcn_mfma_f32_16x16x32_bf16(aq0, kc[2 * s], sf, 0, 0, 0);
            sf = __builtin_amdgcn_mfma_f32_16x16x32_bf16(aq1, kc[2 * s + 1], sf, 0, 0, 0);
            int col = kt * 64 + s * 16 + l15;
            if (col < N) {
                int kh = col / WW, kw = col - kh * WW;
#pragma unroll
                for (int r = 0; r < 4; r++)
                    sv[s][r] = sf[r] * 0.125f
                             + Dh[w][q4 * 4 + r][qhv[r] - kh + HH - 1]
                             + Dw[w][q4 * 4 + r][qwv[r] - kw + WW - 1];
            } else {
#pragma unroll
                for (int r = 0; r < 4; r++) sv[s][r] = -1e30f;
            }
        }
        float p[4][4];
#pragma unroll
        for (int r = 0; r < 4; r++) {
            float t = fmaxf(fmaxf(sv[0][r], sv[1][r]), fmaxf(sv[2][r], sv[3][r]));
#pragma unroll
            for (int off = 1; off < 16; off <<= 1) t = fmaxf(t, __shfl_xor(t, off));
            float mn = fmaxf(m_r[r], t);
            float alpha = __expf(m_r[r] - mn);
            m_r[r] = mn;
            float ps = 0.f;
#pragma unroll
            for (int s = 0; s < 4; s++) { p[s][r] = __expf(sv[s][r] - mn); ps += p[s][r]; }
#pragma unroll
            for (int off = 1; off < 16; off <<= 1) ps += __shfl_xor(ps, off);
            l_r[r] = l_r[r] * alpha + ps;
#pragma unroll
            for (int s = 0; s < 4; s++) acc_o[s][r] *= alpha;
        }
#pragma unroll
        for (int s = 0; s < 4; s++)
#pragma unroll
            for (int r = 0; r < 4; r++)
                Pw[w][(q4 * 4 + r) * 72 + s * 16 + l15] = f2bf(p[s][r]);
        short8 af0 = *(const short8*)(&Pw[w][l15 * 72 + q4 * 8]);
        short8 af1 = *(const short8*)(&Pw[w][l15 * 72 + 32 + q4 * 8]);
#pragma unroll
        for (int s2 = 0; s2 < 4; s2++) {
            acc_o[s2] = __builtin_amdgcn_mfma_f32_16x16x32_bf16(af0, vv[2 * s2], acc_o[s2], 0, 0, 0);
            acc_o[s2] = __builtin_amdgcn_mfma_f32_16x16x32_bf16(af1, vv[2 * s2 + 1], acc_o[s2], 0, 0, 0);
        }
#pragma unroll
        for (int i = 0; i < 8; i++) kc[i] = kn[i];
    }
#pragma unroll
    for (int r = 0; r < 4; r++) {
        int qg = q0 + w * 16 + q4 * 4 + r;
        if (qg >= N) continue;
        float inv = 1.f / l_r[r];
#pragma unroll
        for (int s2 = 0; s2 < 4; s2++)
            out[(size_t)(base + qg) * EMBED + head * 64 + s2 * 16 + l15] =
                f2bf(acc_o[s2][r] * inv);
    }
}

// ---------------- patch-embed im2col (bf16 out, row-major) -----------------
__global__ void im2col_patch(const float* __restrict__ x, unsigned short* __restrict__ A, int n) {
    int i = blockIdx.x * blockDim.x + threadIdx.x;
    if (i >= n) return;
    int t = i / EMBED, kidx = i % EMBED;
    int c = kidx >> 8, r = kidx & 255;
    int ph = r >> 4, pw = r & 15;
    int ty = t >> 5, tx = t & 31;
    A[i] = f2bf(x[(size_t)c * 512 * 512 + (size_t)(ty * 16 + ph) * 512 + (tx * 16 + pw)]);
}

// ---------------- neck 3x3 conv im2col (bf16 out, row-major) ---------------
__global__ void im2col3(const float* __restrict__ in, unsigned short* __restrict__ out, int n) {
    int i = blockIdx.x * blockDim.x + threadIdx.x;
    if (i >= n) return;
    int p = i / 2304, k = i % 2304;
    int c = k / 9, r9 = k % 9;
    int ky = r9 / 3, kx = r9 % 3;
    int py = p >> 5, px = p & 31;
    int ny = py + ky - 1, nx = px + kx - 1;
    float v = (ny >= 0 && ny < TOKS && nx >= 0 && nx < TOKS)
                ? in[(size_t)(ny * TOKS + nx) * OUTC + c] : 0.f;
    out[i] = f2bf(v);
}

// ---------------- host orchestration ---------------------------------------
extern "C" void kernel_launch(void* const* d_in, const int* in_sizes, int n_in,
                              void* d_out, int out_size, void* d_ws, size_t ws_size,
                              hipStream_t stream) {
    const float* x        = (const float*)d_in[0];
    const float* patch_w  = (const float*)d_in[1];
    const float* patch_b  = (const float*)d_in[2];
    const float* pos      = (const float*)d_in[3];
    const float* qkv_w    = (const float*)d_in[4];
    const float* qkv_b    = (const float*)d_in[5];
    const float* proj_w   = (const float*)d_in[6];
    const float* proj_b   = (const float*)d_in[7];
    const float* n1w      = (const float*)d_in[8];
    const float* n1b      = (const float*)d_in[9];
    const float* n2w      = (const float*)d_in[10];
    const float* n2b      = (const float*)d_in[11];
    const float* mlp_w1   = (const float*)d_in[12];
    const float* mlp_b1   = (const float*)d_in[13];
    const float* mlp_w2   = (const float*)d_in[14];
    const float* mlp_b2   = (const float*)d_in[15];
    const float* rhw      = (const float*)d_in[16];
    const float* rww      = (const float*)d_in[17];
    const float* rhg      = (const float*)d_in[18];
    const float* rwg      = (const float*)d_in[19];
    const float* neck_w1  = (const float*)d_in[20];
    const float* nl1w     = (const float*)d_in[21];
    const float* nl1b     = (const float*)d_in[22];
    const float* neck_w2  = (const float*)d_in[23];
    const float* nl2w     = (const float*)d_in[24];
    const float* nl2b     = (const float*)d_in[25];

    const size_t SZ_QKVW = (size_t)2304 * 768;   // per-layer elems (tiled stride identical)
    const size_t SZ_PROJ = (size_t)768 * 768;
    const size_t SZ_MLP1 = (size_t)3072 * 768;
    const size_t SZ_MLP2 = (size_t)768 * 3072;

    char* p = (char*)d_ws;
    float* H    = (float*)p;            p += (size_t)NTOK * EMBED * 4;
    unsigned short* QKVb = (unsigned short*)p; p += (size_t)WTOK * 2304 * 2;
    unsigned short* Vt   = (unsigned short*)p; p += (size_t)NWIN * HEADS * 64 * 208 * 2 + 4096;
    float* LNF  = (float*)p;            p += (size_t)NTOK * OUTC * 4;
    unsigned short* XWw = (unsigned short*)p;  p += (size_t)112 * 12288 * 2;   // tiled, padded to 112 row-blocks
    unsigned short* XWs = (unsigned short*)p;  p += (size_t)64 * 12288 * 2;    // tiled (1024 rows)
    unsigned short* AOb = (unsigned short*)p;  p += (size_t)WTOK * EMBED * 2;
    float* SPK  = (float*)p;            p += (size_t)16 * 1024 * 1024;
    unsigned short* PWb  = (unsigned short*)p; p += SZ_PROJ * 2;
    unsigned short* NW1b = (unsigned short*)p; p += (size_t)OUTC * 768 * 2;
    unsigned short* NW2b = (unsigned short*)p; p += (size_t)OUTC * 2304 * 2;
    unsigned short* MIDB  = QKVb;   // alias: MLP mid 1024x3072 bf16 (row-major)
    unsigned short* CONVA = QKVb;   // alias: neck im2col 1024x2304 bf16 (row-major)

    // all-layer preconverted (tiled) weights if workspace allows
    unsigned short* WQa = (unsigned short*)p;
    size_t needAll = (size_t)(p - (char*)d_ws) +
                     (SZ_QKVW + SZ_PROJ + SZ_MLP1 + SZ_MLP2) * 2 * DEPTH;
    bool pre = ws_size >= needAll;
    unsigned short *WPa, *W1a, *W2a;
    size_t sQ, sP, s1, s2;
    if (pre) {
        WPa = WQa + SZ_QKVW * DEPTH;
        W1a = WPa + SZ_PROJ * DEPTH;
        W2a = W1a + SZ_MLP1 * DEPTH;
        sQ = SZ_QKVW; sP = SZ_PROJ; s1 = SZ_MLP1; s2 = SZ_MLP2;
    } else {
        WPa = WQa + SZ_QKVW;
        W1a = WPa + SZ_PROJ;
        W2a = W1a + SZ_MLP1;
        sQ = sP = s1 = s2 = 0;
    }

    const int NE = NTOK * EMBED;

    zero_pads<<<WTOK, 256, 0, stream>>>(XWw);
    if (pre) {
        convw_all<<<42144, 256, 0, stream>>>(
            qkv_w, proj_w, mlp_w1, mlp_w2, patch_w, neck_w1, neck_w2,
            WQa, WPa, W1a, W2a, PWb, NW1b, NW2b);
    } else {
        convw_one<<<(73728 + 255) / 256, 256, 0, stream>>>(patch_w, PWb, 768, 73728);
        convw_one<<<(24576 + 255) / 256, 256, 0, stream>>>(neck_w1, NW1b, 768, 24576);
        convw_one<<<(73728 + 255) / 256, 256, 0, stream>>>(neck_w2, NW2b, 2304, 73728);
    }

    // ---- patch embed (split-K=2) + fused [sum + patch_b + pos -> H; LN1 -> windowed] ----
    im2col_patch<<<(NE + 255) / 256, 256, 0, stream>>>(x, AOb, NE);
    gemm_rd<0, 2, 6, 0><<<dim3(EMBED / 64, NTOK / 64, 2), 256, 0, stream>>>(
        AOb, PWb, nullptr, SPK, NTOK, EMBED, EMBED, nullptr, 0, 0);
    fuse_ln<2><<<NTOK, 256, 0, stream>>>(
        SPK, (size_t)NTOK * EMBED, 0, pos, patch_b, H, 0, n1w, n1b, XWw, 2);

    for (int i = 0; i < DEPTH; i++) {
        bool glob = (i == 2 || i == 5 || i == 8 || i == 11);
        const unsigned short* wq = WQa + sQ * i;
        const unsigned short* wp = WPa + sP * i;
        const unsigned short* w1 = W1a + s1 * i;
        const unsigned short* w2 = W2a + s2 * i;
        if (!pre) {
            convw_one<<<(2212 * 100 + 255) / 256, 256, 0, stream>>>(
                qkv_w + (size_t)i * SZ_QKVW, WQa, 768, 221184);
            convw_one<<<(73728 + 255) / 256, 256, 0, stream>>>(
                proj_w + (size_t)i * SZ_PROJ, WPa, 768, 73728);
            convw_one<<<(294912 + 255) / 256, 256, 0, stream>>>(
                mlp_w1 + (size_t)i * SZ_MLP1, W1a, 768, 294912);
            convw_one<<<(294912 + 255) / 256, 256, 0, stream>>>(
                mlp_w2 + (size_t)i * SZ_MLP2, W2a, 3072, 294912);
        }

        if (!glob) {
            gemm_rd<3, 1, 12, 1><<<dim3(2304 / 64, (WTOK + 63) / 64), 256, 0, stream>>>(
                XWw, wq, qkv_b + i * 2304, QKVb, WTOK, 2304, EMBED, Vt, WN, 208);
            attn_mfma<WN, WINSZ, WINSZ, 208><<<dim3(4, NWIN * HEADS), 256, 0, stream>>>(
                QKVb, Vt, rhw + (size_t)i * 27 * 64, rww + (size_t)i * 27 * 64, AOb);
            gemm_rd<0, 2, 6, 0><<<dim3(EMBED / 64, (WTOK + 63) / 64, 2), 256, 0, stream>>>(
                AOb, wp, nullptr, SPK, WTOK, EMBED, EMBED, nullptr, 0, 0);
            fuse_ln<2><<<NTOK, 256, 0, stream>>>(
                SPK, (size_t)WTOK * EMBED, 1, nullptr, proj_b + i * EMBED, H, 1,
                n2w + i * EMBED, n2b + i * EMBED, XWs, 1);
        } else {
            gemm_rd<3, 1, 12, 1><<<dim3(2304 / 64, NTOK / 64), 256, 0, stream>>>(
                XWs, wq, qkv_b + i * 2304, QKVb, NTOK, 2304, EMBED, Vt, NTOK, NTOK);
            attn_mfma<NTOK, TOKS, TOKS, NTOK><<<dim3(16, HEADS), 256, 0, stream>>>(
                QKVb, Vt, rhg + (size_t)i * 63 * 64, rwg + (size_t)i * 63 * 64, AOb);
            gemm_rd<0, 2, 6, 0><<<dim3(EMBED / 64, NTOK / 64, 2), 256, 0, stream>>>(
                AOb, wp, nullptr, SPK, NTOK, EMBED, EMBED, nullptr, 0, 0);
            fuse_ln<2><<<NTOK, 256, 0, stream>>>(
                SPK, (size_t)NTOK * EMBED, 0, nullptr, proj_b + i * EMBED, H, 1,
                n2w + i * EMBED, n2b + i * EMBED, XWs, 1);
        }
        // MLP
        gemm_rd<2, 1, 12, 1><<<dim3(MLPDIM / 64, NTOK / 64), 256, 0, stream>>>(
            XWs, w1, mlp_b1 + i * MLPDIM, MIDB, NTOK, MLPDIM, EMBED, nullptr, 0, 0);
        gemm_rd<0, 4, 12, 0><<<dim3(EMBED / 64, NTOK / 64, 4), 256, 0, stream>>>(
            MIDB, w2, nullptr, SPK, NTOK, EMBED, MLPDIM, nullptr, 0, 0);
        int nlnmode; const float* nw; const float* nb2; unsigned short* ndst;
        if (i == DEPTH - 1) { nlnmode = 3; nw = n1w; nb2 = n1b; ndst = XWs; }
        else {
            bool nglob = (i + 1 == 2 || i + 1 == 5 || i + 1 == 8 || i + 1 == 11);
            nlnmode = nglob ? 1 : 2;
            nw = n1w + (size_t)(i + 1) * EMBED; nb2 = n1b + (size_t)(i + 1) * EMBED;
            ndst = nglob ? XWs : XWw;
        }
        fuse_ln<4><<<NTOK, 256, 0, stream>>>(
            SPK, (size_t)NTOK * EMBED, 0, nullptr, mlp_b2 + i * EMBED, H, 1,
            nw, nb2, ndst, nlnmode);
    }

    // ---- neck ----
    gemm_rd<0, 4, 3, 1><<<dim3(OUTC / 64, NTOK / 64, 4), 256, 0, stream>>>(
        XWs, NW1b, nullptr, SPK, NTOK, OUTC, EMBED, nullptr, 0, 0);
    fuse_ln_neck<4><<<NTOK, 256, 0, stream>>>(SPK, nl1w, nl1b, LNF, NTOK, 0);
    im2col3<<<(NTOK * 2304 + 255) / 256, 256, 0, stream>>>(LNF, CONVA, NTOK * 2304);
    gemm_rd<0, 6, 6, 0><<<dim3(OUTC / 64, NTOK / 64, 6), 256, 0, stream>>>(
        CONVA, NW2b, nullptr, SPK, NTOK, OUTC, 2304, nullptr, 0, 0);
    fuse_ln_neck<6><<<NTOK, 256, 0, stream>>>(SPK, nl2w, nl2b, (float*)d_out, NTOK, 1);
}

// Round 10
// 1621.267 us; speedup vs baseline: 1.5696x; 1.0875x over previous
//
#include <hip/hip_runtime.h>
#include <math.h>

#define EMBED   768
#define HEADS   12
#define DEPTH   12
#define TOKS    32
#define NTOK    1024
#define WINSZ   14
#define NWIN    9
#define WTOK    1764        // 9*196
#define WN      196
#define WPITCH  256         // padded window row pitch (16-block + 64-tile aligned)
#define MLPDIM  3072
#define OUTC    256
#define LNEPS   1e-6f

typedef __attribute__((ext_vector_type(8))) short short8;
typedef __attribute__((ext_vector_type(4))) float float4v;

__device__ __forceinline__ unsigned short f2bf(float f) {
    unsigned u = __float_as_uint(f);
    unsigned r = (u + 0x7fffu + ((u >> 16) & 1u)) >> 16;
    return (unsigned short)r;
}
__device__ __forceinline__ float bf2f(unsigned short s) {
    return __uint_as_float((unsigned)s << 16);
}
// packed f32->bf16 (RNE, identical to f2bf)
__device__ __forceinline__ unsigned cvtpk(float a, float b) {
    unsigned r;
    asm("v_cvt_pk_bf16_f32 %0, %1, %2" : "=v"(r) : "v"(a), "v"(b));
    return r;
}
__device__ __forceinline__ short8 pk8(float4 a, float4 b) {
    union { unsigned u[4]; short8 s; } t;
    t.u[0] = cvtpk(a.x, a.y); t.u[1] = cvtpk(a.z, a.w);
    t.u[2] = cvtpk(b.x, b.y); t.u[3] = cvtpk(b.z, b.w);
    return t.s;
}
// global row p (0..1023) -> window-token index
__device__ __forceinline__ int winidx(int p) {
    int gy = p >> 5, gx = p & 31;
    return ((gy / WINSZ) * 3 + gx / WINSZ) * WN + (gy % WINSZ) * WINSZ + (gx % WINSZ);
}

// =================== fragment-tiled layout ==================================
// T'[(row/16)(col/8)(row%16)][8]: elem off = ((rb*(K/8)+kc)*16 + rl)*8 + (c&7)
// A wave's MFMA fragment load (lane = q4*16+l15) is ONE contiguous 1KB access.

// whole-model weight conversion f32 -> tiled bf16, ONE launch.
// Block-per-16x128-tile with LDS transpose staging: reads 16 rows x 512B
// CONTIGUOUSLY, writes the tiled output PERFECTLY LINEARLY (4KB/block).
// Block counts: qkv 10368 | proj 3456 | mlp1 13824 | mlp2 13824 | patch 288 |
// neck1 96 | neck2 288  = 42144.
__global__ __launch_bounds__(256) void convw_all(
        const float* __restrict__ q,  const float* __restrict__ pr,
        const float* __restrict__ m1, const float* __restrict__ m2,
        const float* __restrict__ pw, const float* __restrict__ n1,
        const float* __restrict__ n2,
        unsigned short* __restrict__ oq,  unsigned short* __restrict__ opr,
        unsigned short* __restrict__ om1, unsigned short* __restrict__ om2,
        unsigned short* __restrict__ opw, unsigned short* __restrict__ on1,
        unsigned short* __restrict__ on2) {
    __shared__ unsigned short L[16][136];   // +8 pad
    int g = blockIdx.x;
    const float* s; unsigned short* o; int blk; int K;
    if (g < 10368)       { s = q;  o = oq;  blk = g;         K = 768;  }
    else if (g < 13824)  { s = pr; o = opr; blk = g - 10368; K = 768;  }
    else if (g < 27648)  { s = m1; o = om1; blk = g - 13824; K = 768;  }
    else if (g < 41472)  { s = m2; o = om2; blk = g - 27648; K = 3072; }
    else if (g < 41760)  { s = pw; o = opw; blk = g - 41472; K = 768;  }
    else if (g < 41856)  { s = n1; o = on1; blk = g - 41760; K = 768;  }
    else                 { s = n2; o = on2; blk = g - 41856; K = 2304; }
    int nkb = K >> 7;                       // 128-col blocks per row
    int rb = blk / nkb, kcb = blk - rb * nkb;
    int t = threadIdx.x;
    // read phase: 16 threads per row, 128 contiguous floats per row
    {
        int rl = t >> 4, cl = (t & 15) * 8;
        const float* sp = s + (size_t)(rb * 16 + rl) * K + kcb * 128 + cl;
        float4 v0 = *(const float4*)sp, v1 = *(const float4*)(sp + 4);
        *(short8*)&L[rl][cl] = pk8(v0, v1);
    }
    __syncthreads();
    // write phase: fully linear 4KB store
    {
        int kc_l = t >> 4, rw = t & 15;
        short8 vv = *(const short8*)&L[rw][kc_l * 8];
        *(short8*)(o + ((size_t)(rb * (K >> 3) + kcb * 16 + kc_l) * 16 + rw) * 8) = vv;
    }
}

// single-tensor tiled conversion (fallback path only)
__global__ __launch_bounds__(256) void convw_one(
        const float* __restrict__ in, unsigned short* __restrict__ out,
        int K, int nchunk) {
    int g = blockIdx.x * 256 + threadIdx.x;
    if (g >= nchunk) return;
    int twoK = 2 * K;
    int rb = g / twoK, rem = g - rb * twoK;
    int kc = rem >> 4, rl = rem & 15;
    const float* sp = in + (size_t)(rb * 16 + rl) * K + kc * 8;
    float4 v0 = *(const float4*)sp, v1 = *(const float4*)(sp + 4);
    *(short8*)(out + (size_t)g * 8) = pk8(v0, v1);
}

// zero the pad rows of the windowed LN buffer (tiled layout, once)
__global__ __launch_bounds__(256) void zero_pads(unsigned short* __restrict__ XWw) {
    int t = blockIdx.x;                    // 0..1763
    int w = t / WN, r = t % WN;
    int gy = (w / 3) * WINSZ + r / WINSZ, gx = (w % 3) * WINSZ + r % WINSZ;
    if (gy < TOKS && gx < TOKS) return;
    unsigned short* dst = XWw + (size_t)(t >> 4) * 12288 + (size_t)(t & 15) * 8;
    for (int c = threadIdx.x; c < EMBED; c += 256)
        dst[(size_t)(c >> 3) * 128 + (c & 7)] = 0;
}

// ---------------- register-direct MFMA GEMM, tiled operands ----------------
// C[M,N] = A[M,K] @ B[N,K]^T + bias. Barrier-free, LDS-free; 4 waves; block
// tile 64x64 (wave 32x32); 3-slot rolling prefetch; XCD-bijective swizzle.
// B ALWAYS fragment-tiled; A tiled iff AT==1 (now: all call sites).
// OMODE: 0 = f32 out, 2 = bf16+GELU TILED out, 3 = qkv split
// SPLIT>1: grid.z splits K; partial f32 written to Cout + z*M*N (no bias).
#define LDT(S, KO) do {                                               \
    _Pragma("unroll")                                                 \
    for (int i_ = 0; i_ < 2; i_++) {                                  \
        a_##S[i_][0] = *(const short8*)(ap[i_] + (size_t)(KO) * AKS); \
        a_##S[i_][1] = *(const short8*)(ap[i_] + (size_t)(KO) * AKS + 32 * AKS); } \
    _Pragma("unroll")                                                 \
    for (int j_ = 0; j_ < 2; j_++) {                                  \
        b_##S[j_][0] = *(const short8*)(bp[j_] + (size_t)(KO) * 16);  \
        b_##S[j_][1] = *(const short8*)(bp[j_] + (size_t)(KO) * 16 + 512); } \
} while (0)

#define MFMA_SLOT(S) do {                                       \
    _Pragma("unroll")                                           \
    for (int h_ = 0; h_ < 2; h_++)                              \
        _Pragma("unroll")                                       \
        for (int i_ = 0; i_ < 2; i_++)                          \
            _Pragma("unroll")                                   \
            for (int j_ = 0; j_ < 2; j_++)                      \
                acc[i_][j_] = __builtin_amdgcn_mfma_f32_16x16x32_bf16( \
                    a_##S[i_][h_], b_##S[j_][h_], acc[i_][j_], 0, 0, 0); \
} while (0)

template<int OMODE, int SPLIT, int NT, int AT>
__global__ __launch_bounds__(256) void gemm_rd(
        const unsigned short* __restrict__ A, const unsigned short* __restrict__ B,
        const float* __restrict__ bias, void* __restrict__ Cout,
        int M, int N, int K,
        unsigned short* __restrict__ vout, int VN, int VNP) {
    const int tid = threadIdx.x, lane = tid & 63, wave = tid >> 6;
    const int wm = wave >> 1, wn = wave & 1;
    const int l15 = lane & 15, q4 = lane >> 4;
    const int AKS = AT ? 16 : 1;

    // ---- XCD-aware bijective swizzle (m204), m-fastest decode ----
    const int gx = gridDim.x, gy = gridDim.y;
    const int nb = gx * gy;
    const int f  = blockIdx.y * gx + blockIdx.x;
    const int qq = nb >> 3, rr = nb & 7;
    const int xcd = f & 7, sl = f >> 3;
    const int wg = (xcd < rr) ? xcd * (qq + 1) + sl
                              : rr * (qq + 1) + (xcd - rr) * qq + sl;
    const int bn = wg / gy;
    const int bm = wg - bn * gy;

    const int m0 = bm * 64 + wm * 32;
    const int n0 = bn * 64 + wn * 32;
    const int kb = blockIdx.z * (NT * 64);
    const int Kc8 = K >> 3;

    const unsigned short* ap[2];
    if (AT) {
#pragma unroll
        for (int i = 0; i < 2; i++) {
            int mb = (m0 + i * 16) >> 4;
            ap[i] = A + ((size_t)mb * Kc8 + (kb >> 3)) * 128 + q4 * 128 + l15 * 8;
        }
    } else {
#pragma unroll
        for (int i = 0; i < 2; i++) {
            int gm = m0 + i * 16 + l15; if (gm >= M) gm = M - 1;
            ap[i] = A + (size_t)gm * K + kb + q4 * 8;
        }
    }
    const unsigned short* bp[2];
#pragma unroll
    for (int j = 0; j < 2; j++) {
        int nb2 = (n0 + j * 16) >> 4;
        bp[j] = B + ((size_t)nb2 * Kc8 + (kb >> 3)) * 128 + q4 * 128 + l15 * 8;
    }

    float4v acc[2][2];
#pragma unroll
    for (int i = 0; i < 2; i++)
#pragma unroll
        for (int j = 0; j < 2; j++) acc[i][j] = (float4v){0.f, 0.f, 0.f, 0.f};

    short8 a_0[2][2], b_0[2][2];
    short8 a_1[2][2], b_1[2][2];
    short8 a_2[2][2], b_2[2][2];

    LDT(0, 0);
    LDT(1, 64);
#pragma unroll
    for (int k = 0; k + 3 < NT; k += 3) {
        LDT(2, (k + 2) * 64); MFMA_SLOT(0);
        LDT(0, (k + 3) * 64); MFMA_SLOT(1);
        LDT(1, (k + 4) * 64); MFMA_SLOT(2);
    }
    LDT(2, (NT - 1) * 64);
    MFMA_SLOT(0); MFMA_SLOT(1); MFMA_SLOT(2);

    if (SPLIT > 1) {
        float* P = (float*)Cout + (size_t)blockIdx.z * M * N;
#pragma unroll
        for (int i = 0; i < 2; i++)
#pragma unroll
            for (int r = 0; r < 4; r++) {
                int m = m0 + i * 16 + q4 * 4 + r;
                if (m >= M) continue;
#pragma unroll
                for (int j = 0; j < 2; j++)
                    P[(size_t)m * N + n0 + j * 16 + l15] = acc[i][j][r];
            }
        return;
    }
#pragma unroll
    for (int i = 0; i < 2; i++) {
        int mb = m0 + i * 16 + q4 * 4;
#pragma unroll
        for (int j = 0; j < 2; j++) {
            int n = n0 + j * 16 + l15;
            float bv = bias ? bias[n] : 0.f;
            if (OMODE == 3 && n >= 1536) {
                int nn = n - 1536;
                int head = nn >> 6, dd = nn & 63;
                if (mb + 3 < M) {
                    int win = mb / VN, mt = mb - win * VN;
                    ushort4 o;
                    o.x = f2bf(acc[i][j][0] + bv);
                    o.y = f2bf(acc[i][j][1] + bv);
                    o.z = f2bf(acc[i][j][2] + bv);
                    o.w = f2bf(acc[i][j][3] + bv);
                    *(ushort4*)(vout + (size_t)((win * HEADS + head) * 64 + dd) * VNP + mt) = o;
                } else {
#pragma unroll
                    for (int r = 0; r < 4; r++) {
                        int m = mb + r;
                        if (m >= M) continue;
                        int win = m / VN, mt = m - win * VN;
                        vout[(size_t)((win * HEADS + head) * 64 + dd) * VNP + mt] =
                            f2bf(acc[i][j][r] + bv);
                    }
                }
                continue;
            }
#pragma unroll
            for (int r = 0; r < 4; r++) {
                int m = mb + r;
                if (m >= M) continue;
                float v = acc[i][j][r] + bv;
                if (OMODE == 0) {
                    ((float*)Cout)[(size_t)m * N + n] = v;
                } else if (OMODE == 2) {
                    v = 0.5f * v * (1.f + erff(v * 0.70710678118654752f));
                    ((unsigned short*)Cout)[((size_t)(m >> 4) * (N >> 3) + (n >> 3)) * 128
                                            + (m & 15) * 8 + (n & 7)] = f2bf(v);
                } else {  // OMODE 3, n < 1536
                    ((unsigned short*)Cout)[(size_t)m * 2304 + n] = f2bf(v);
                }
            }
        }
    }
}

// ---------------- fused reduce + bias + residual + LayerNorm ---------------
// One block per global row p. LN(h) -> lnout FRAGMENT-TILED bf16 (K=768).
// partwin: partial rows use padded window index win*WPITCH + r.
template<int S>
__global__ __launch_bounds__(256) void fuse_ln(
        const float* __restrict__ part, size_t pstride, int partwin,
        const float* __restrict__ extra, const float* __restrict__ bias,
        float* __restrict__ H, int addH,
        const float* __restrict__ lnw, const float* __restrict__ lnb,
        unsigned short* __restrict__ lnout, int lnmode) {
    const int p = blockIdx.x;
    const int tw = winidx(p);
    const int tp = partwin ? ((tw / WN) * WPITCH + (tw % WN)) : p;
    const int c0 = threadIdx.x;
    float h[3];
    float s1 = 0.f, s2 = 0.f;
#pragma unroll
    for (int j = 0; j < 3; j++) {
        int c = c0 + j * 256;
        float v = 0.f;
        if (S > 0) {
            v = part[(size_t)tp * EMBED + c];
#pragma unroll
            for (int z = 1; z < S; z++) v += part[(size_t)z * pstride + (size_t)tp * EMBED + c];
            v += bias[c];
        }
        if (extra) v += extra[(size_t)p * EMBED + c];
        if (addH)  v += H[(size_t)p * EMBED + c];
        h[j] = v;
        if (S > 0) H[(size_t)p * EMBED + c] = v;
        s1 += v; s2 += v * v;
    }
    for (int off = 32; off; off >>= 1) {
        s1 += __shfl_down(s1, off);
        s2 += __shfl_down(s2, off);
    }
    __shared__ float sh1[4], sh2[4];
    __shared__ float smu, srstd;
    int wv = threadIdx.x >> 6, ln = threadIdx.x & 63;
    if (ln == 0) { sh1[wv] = s1; sh2[wv] = s2; }
    __syncthreads();
    if (threadIdx.x == 0) {
        float t1 = sh1[0] + sh1[1] + sh1[2] + sh1[3];
        float t2 = sh2[0] + sh2[1] + sh2[2] + sh2[3];
        float m = t1 / (float)EMBED;
        smu = m; srstd = rsqrtf(t2 / (float)EMBED - m * m + LNEPS);
    }
    __syncthreads();
    float m = smu, r = srstd;
    int R = (lnmode == 2) ? tw : p;
    unsigned short* dst = lnout + (size_t)(R >> 4) * 12288 + (size_t)(R & 15) * 8;
#pragma unroll
    for (int j = 0; j < 3; j++) {
        int c = c0 + j * 256;
        float v = (lnmode == 3) ? h[j] : (h[j] - m) * r * lnw[c] + lnb[c];
        dst[(size_t)(c >> 3) * 128 + (c & 7)] = f2bf(v);
    }
}

// ---------------- fused neck reduce + LayerNorm (C=256) --------------------
template<int S>
__global__ __launch_bounds__(256) void fuse_ln_neck(
        const float* __restrict__ part, const float* __restrict__ w,
        const float* __restrict__ b, float* __restrict__ out, int M, int mode) {
    const int row = blockIdx.x, c = threadIdx.x;
    float v = part[(size_t)row * OUTC + c];
#pragma unroll
    for (int z = 1; z < S; z++)
        v += part[(size_t)z * M * OUTC + (size_t)row * OUTC + c];
    float s1 = v, s2 = v * v;
    for (int off = 32; off; off >>= 1) {
        s1 += __shfl_down(s1, off);
        s2 += __shfl_down(s2, off);
    }
    __shared__ float sh1[4], sh2[4];
    __shared__ float smu, srs;
    int wv = threadIdx.x >> 6, ln = threadIdx.x & 63;
    if (ln == 0) { sh1[wv] = s1; sh2[wv] = s2; }
    __syncthreads();
    if (threadIdx.x == 0) {
        float t1 = sh1[0] + sh1[1] + sh1[2] + sh1[3];
        float t2 = sh2[0] + sh2[1] + sh2[2] + sh2[3];
        float m = t1 / (float)OUTC;
        smu = m; srs = rsqrtf(t2 / (float)OUTC - m * m + LNEPS);
    }
    __syncthreads();
    float res = (v - smu) * srs * w[c] + b[c];
    if (mode == 0) out[(size_t)row * OUTC + c] = res;
    else           out[(size_t)c * M + row] = res;
}

// ---------------- fused MFMA flash attention -------------------------------
// Output written FRAGMENT-TILED at padded row rowT = winI*ROWP + qg.
template<int N, int HH, int WW, int VNP, int ROWP>
__global__ __launch_bounds__(256) void attn_mfma(
        const unsigned short* __restrict__ qkv, const unsigned short* __restrict__ vt,
        const float* __restrict__ rel_h, const float* __restrict__ rel_w,
        unsigned short* __restrict__ out) {
    constexpr int NT = (N + 63) / 64;
    constexpr int JH = ((2 * HH - 1 + 15) / 16) * 16;
    constexpr int JW = ((2 * WW - 1 + 15) / 16) * 16;
    __shared__ unsigned short Pw[4][16 * 72];
    __shared__ float Dh[4][16][JH];
    __shared__ float Dw[4][16][JW];
    const int tid = threadIdx.x, lane = tid & 63, w = tid >> 6;
    const int l15 = lane & 15, q4 = lane >> 4;
    const int bh = blockIdx.y, winI = bh / HEADS, head = bh % HEADS;
    const int base = winI * N;
    const int q0 = blockIdx.x * 64;

    short8 aq0, aq1;
    {
        int qr = q0 + w * 16 + l15; if (qr >= N) qr = N - 1;
        const unsigned short* qp = qkv + (size_t)(base + qr) * 2304 + head * 64;
        aq0 = *(const short8*)(qp + q4 * 8);
        aq1 = *(const short8*)(qp + 32 + q4 * 8);
    }

#pragma unroll
    for (int s = 0; s < JH / 16; s++) {
        int j = s * 16 + l15; if (j > 2 * HH - 2) j = 2 * HH - 2;
        const float* rp = rel_h + (size_t)j * 64 + q4 * 8;
        float4 r0 = *(const float4*)rp;
        float4 r1 = *(const float4*)(rp + 4);
        float4 r2 = *(const float4*)(rp + 32);
        float4 r3 = *(const float4*)(rp + 36);
        short8 b0 = pk8(r0, r1), b1 = pk8(r2, r3);
        float4v df = (float4v){0.f, 0.f, 0.f, 0.f};
        df = __builtin_amdgcn_mfma_f32_16x16x32_bf16(aq0, b0, df, 0, 0, 0);
        df = __builtin_amdgcn_mfma_f32_16x16x32_bf16(aq1, b1, df, 0, 0, 0);
#pragma unroll
        for (int r = 0; r < 4; r++) Dh[w][q4 * 4 + r][s * 16 + l15] = df[r];
    }
#pragma unroll
    for (int s = 0; s < JW / 16; s++) {
        int j = s * 16 + l15; if (j > 2 * WW - 2) j = 2 * WW - 2;
        const float* rp = rel_w + (size_t)j * 64 + q4 * 8;
        float4 r0 = *(const float4*)rp;
        float4 r1 = *(const float4*)(rp + 4);
        float4 r2 = *(const float4*)(rp + 32);
        float4 r3 = *(const float4*)(rp + 36);
        short8 b0 = pk8(r0, r1), b1 = pk8(r2, r3);
        float4v df = (float4v){0.f, 0.f, 0.f, 0.f};
        df = __builtin_amdgcn_mfma_f32_16x16x32_bf16(aq0, b0, df, 0, 0, 0);
        df = __builtin_amdgcn_mfma_f32_16x16x32_bf16(aq1, b1, df, 0, 0, 0);
#pragma unroll
        for (int r = 0; r < 4; r++) Dw[w][q4 * 4 + r][s * 16 + l15] = df[r];
    }

    int qhv[4], qwv[4];
#pragma unroll
    for (int r = 0; r < 4; r++) {
        int qg = q0 + w * 16 + q4 * 4 + r;
        qhv[r] = qg / WW;
        qwv[r] = qg - qhv[r] * WW;
    }

    float m_r[4], l_r[4];
    float4v acc_o[4];
#pragma unroll
    for (int r = 0; r < 4; r++) { m_r[r] = -1e30f; l_r[r] = 0.f; }
#pragma unroll
    for (int s = 0; s < 4; s++) acc_o[s] = (float4v){0.f, 0.f, 0.f, 0.f};

    const unsigned short* vbase = vt + (size_t)bh * 64 * VNP;
    const unsigned short* kqbase = qkv + (size_t)base * 2304 + 768 + head * 64;

    short8 kc[8];
#pragma unroll
    for (int s = 0; s < 4; s++) {
        int kr = s * 16 + l15; if (kr >= N) kr = N - 1;
        const unsigned short* kp = kqbase + (size_t)kr * 2304;
        kc[2 * s]     = *(const short8*)(kp + q4 * 8);
        kc[2 * s + 1] = *(const short8*)(kp + 32 + q4 * 8);
    }

    for (int kt = 0; kt < NT; kt++) {
        short8 vv[8];
        {
            const unsigned short* vb = vbase + kt * 64;
#pragma unroll
            for (int s2 = 0; s2 < 4; s2++) {
                const unsigned short* vr = vb + (size_t)(s2 * 16 + l15) * VNP;
                vv[2 * s2]     = *(const short8*)(vr + q4 * 8);
                vv[2 * s2 + 1] = *(const short8*)(vr + 32 + q4 * 8);
            }
        }
        short8 kn[8];
        {
            int ktn = (kt + 1 < NT) ? kt + 1 : kt;
#pragma unroll
            for (int s = 0; s < 4; s++) {
                int kr = ktn * 64 + s * 16 + l15; if (kr >= N) kr = N - 1;
                const unsigned short* kp = kqbase + (size_t)kr * 2304;
                kn[2 * s]     = *(const short8*)(kp + q4 * 8);
                kn[2 * s + 1] = *(const short8*)(kp + 32 + q4 * 8);
            }
        }
        float sv[4][4];
#pragma unroll
        for (int s = 0; s < 4; s++) {
            float4v sf = (float4v){0.f, 0.f, 0.f, 0.f};
            sf = __builtin_amdgcn_mfma_f32_16x16x32_bf16(aq0, kc[2 * s], sf, 0, 0, 0);
            sf = __builtin_amdgcn_mfma_f32_16x16x32_bf16(aq1, kc[2 * s + 1], sf, 0, 0, 0);
            int col = kt * 64 + s * 16 + l15;
            if (col < N) {
                int kh = col / WW, kw = col - kh * WW;
#pragma unroll
                for (int r = 0; r < 4; r++)
                    sv[s][r] = sf[r] * 0.125f
                             + Dh[w][q4 * 4 + r][qhv[r] - kh + HH - 1]
                             + Dw[w][q4 * 4 + r][qwv[r] - kw + WW - 1];
            } else {
#pragma unroll
                for (int r = 0; r < 4; r++) sv[s][r] = -1e30f;
            }
        }
        float p[4][4];
#pragma unroll
        for (int r = 0; r < 4; r++) {
            float t = fmaxf(fmaxf(sv[0][r], sv[1][r]), fmaxf(sv[2][r], sv[3][r]));
#pragma unroll
            for (int off = 1; off < 16; off <<= 1) t = fmaxf(t, __shfl_xor(t, off));
            float mn = fmaxf(m_r[r], t);
            float alpha = __expf(m_r[r] - mn);
            m_r[r] = mn;
            float ps = 0.f;
#pragma unroll
            for (int s = 0; s < 4; s++) { p[s][r] = __expf(sv[s][r] - mn); ps += p[s][r]; }
#pragma unroll
            for (int off = 1; off < 16; off <<= 1) ps += __shfl_xor(ps, off);
            l_r[r] = l_r[r] * alpha + ps;
#pragma unroll
            for (int s = 0; s < 4; s++) acc_o[s][r] *= alpha;
        }
#pragma unroll
        for (int s = 0; s < 4; s++)
#pragma unroll
            for (int r = 0; r < 4; r++)
                Pw[w][(q4 * 4 + r) * 72 + s * 16 + l15] = f2bf(p[s][r]);
        short8 af0 = *(const short8*)(&Pw[w][l15 * 72 + q4 * 8]);
        short8 af1 = *(const short8*)(&Pw[w][l15 * 72 + 32 + q4 * 8]);
#pragma unroll
        for (int s2 = 0; s2 < 4; s2++) {
            acc_o[s2] = __builtin_amdgcn_mfma_f32_16x16x32_bf16(af0, vv[2 * s2], acc_o[s2], 0, 0, 0);
            acc_o[s2] = __builtin_amdgcn_mfma_f32_16x16x32_bf16(af1, vv[2 * s2 + 1], acc_o[s2], 0, 0, 0);
        }
#pragma unroll
        for (int i = 0; i < 8; i++) kc[i] = kn[i];
    }
    // ---- store, fragment-tiled at padded row winI*ROWP + qg ----
#pragma unroll
    for (int r = 0; r < 4; r++) {
        int qg = q0 + w * 16 + q4 * 4 + r;
        if (qg >= N) continue;
        int rowT = winI * ROWP + qg;
        float inv = 1.f / l_r[r];
        unsigned short* dst = out + (size_t)(rowT >> 4) * 12288 + (size_t)(rowT & 15) * 8;
#pragma unroll
        for (int s2 = 0; s2 < 4; s2++) {
            int col = head * 64 + s2 * 16 + l15;
            dst[(size_t)(col >> 3) * 128 + (col & 7)] = f2bf(acc_o[s2][r] * inv);
        }
    }
}

// ---------------- patch-embed im2col (fragment-tiled bf16 out) -------------
__global__ void im2col_patch(const float* __restrict__ x, unsigned short* __restrict__ A, int n) {
    int i = blockIdx.x * blockDim.x + threadIdx.x;
    if (i >= n) return;
    int t = i / EMBED, kidx = i % EMBED;
    int c = kidx >> 8, r = kidx & 255;
    int ph = r >> 4, pw = r & 15;
    int ty = t >> 5, tx = t & 31;
    float v = x[(size_t)c * 512 * 512 + (size_t)(ty * 16 + ph) * 512 + (tx * 16 + pw)];
    A[((size_t)(t >> 4) * 96 + (kidx >> 3)) * 128 + (t & 15) * 8 + (kidx & 7)] = f2bf(v);
}

// ---------------- neck 3x3 conv im2col (fragment-tiled bf16 out) -----------
__global__ void im2col3(const float* __restrict__ in, unsigned short* __restrict__ out, int n) {
    int i = blockIdx.x * blockDim.x + threadIdx.x;
    if (i >= n) return;
    int p = i / 2304, k = i % 2304;
    int c = k / 9, r9 = k % 9;
    int ky = r9 / 3, kx = r9 % 3;
    int py = p >> 5, px = p & 31;
    int ny = py + ky - 1, nx = px + kx - 1;
    float v = (ny >= 0 && ny < TOKS && nx >= 0 && nx < TOKS)
                ? in[(size_t)(ny * TOKS + nx) * OUTC + c] : 0.f;
    out[((size_t)(p >> 4) * 288 + (k >> 3)) * 128 + (p & 15) * 8 + (k & 7)] = f2bf(v);
}

// ---------------- host orchestration ---------------------------------------
extern "C" void kernel_launch(void* const* d_in, const int* in_sizes, int n_in,
                              void* d_out, int out_size, void* d_ws, size_t ws_size,
                              hipStream_t stream) {
    const float* x        = (const float*)d_in[0];
    const float* patch_w  = (const float*)d_in[1];
    const float* patch_b  = (const float*)d_in[2];
    const float* pos      = (const float*)d_in[3];
    const float* qkv_w    = (const float*)d_in[4];
    const float* qkv_b    = (const float*)d_in[5];
    const float* proj_w   = (const float*)d_in[6];
    const float* proj_b   = (const float*)d_in[7];
    const float* n1w      = (const float*)d_in[8];
    const float* n1b      = (const float*)d_in[9];
    const float* n2w      = (const float*)d_in[10];
    const float* n2b      = (const float*)d_in[11];
    const float* mlp_w1   = (const float*)d_in[12];
    const float* mlp_b1   = (const float*)d_in[13];
    const float* mlp_w2   = (const float*)d_in[14];
    const float* mlp_b2   = (const float*)d_in[15];
    const float* rhw      = (const float*)d_in[16];
    const float* rww      = (const float*)d_in[17];
    const float* rhg      = (const float*)d_in[18];
    const float* rwg      = (const float*)d_in[19];
    const float* neck_w1  = (const float*)d_in[20];
    const float* nl1w     = (const float*)d_in[21];
    const float* nl1b     = (const float*)d_in[22];
    const float* neck_w2  = (const float*)d_in[23];
    const float* nl2w     = (const float*)d_in[24];
    const float* nl2b     = (const float*)d_in[25];

    const size_t SZ_QKVW = (size_t)2304 * 768;
    const size_t SZ_PROJ = (size_t)768 * 768;
    const size_t SZ_MLP1 = (size_t)3072 * 768;
    const size_t SZ_MLP2 = (size_t)768 * 3072;
    const int MPAD = NWIN * WPITCH;       // 2304 padded windowed rows

    char* p = (char*)d_ws;
    float* H    = (float*)p;            p += (size_t)NTOK * EMBED * 4;
    unsigned short* QKVb = (unsigned short*)p; p += (size_t)WTOK * 2304 * 2;
    unsigned short* Vt   = (unsigned short*)p; p += (size_t)NWIN * HEADS * 64 * 208 * 2 + 4096;
    float* LNF  = (float*)p;            p += (size_t)NTOK * OUTC * 4;
    unsigned short* XWw = (unsigned short*)p;  p += (size_t)112 * 12288 * 2;   // tiled, 112 row-blocks
    unsigned short* XWs = (unsigned short*)p;  p += (size_t)64 * 12288 * 2;    // tiled (1024 rows)
    unsigned short* AOb = (unsigned short*)p;  p += (size_t)144 * 96 * 128 * 2; // tiled, 144 row-blocks (MPAD)
    float* SPK  = (float*)p;            p += (size_t)16 * 1024 * 1024;
    unsigned short* PWb  = (unsigned short*)p; p += SZ_PROJ * 2;
    unsigned short* NW1b = (unsigned short*)p; p += (size_t)OUTC * 768 * 2;
    unsigned short* NW2b = (unsigned short*)p; p += (size_t)OUTC * 2304 * 2;
    unsigned short* MIDB  = QKVb;   // alias: MLP mid 1024x3072 tiled bf16
    unsigned short* CONVA = QKVb;   // alias: neck im2col 1024x2304 tiled bf16

    // all-layer preconverted (tiled) weights if workspace allows
    unsigned short* WQa = (unsigned short*)p;
    size_t needAll = (size_t)(p - (char*)d_ws) +
                     (SZ_QKVW + SZ_PROJ + SZ_MLP1 + SZ_MLP2) * 2 * DEPTH;
    bool pre = ws_size >= needAll;
    unsigned short *WPa, *W1a, *W2a;
    size_t sQ, sP, s1, s2;
    if (pre) {
        WPa = WQa + SZ_QKVW * DEPTH;
        W1a = WPa + SZ_PROJ * DEPTH;
        W2a = W1a + SZ_MLP1 * DEPTH;
        sQ = SZ_QKVW; sP = SZ_PROJ; s1 = SZ_MLP1; s2 = SZ_MLP2;
    } else {
        WPa = WQa + SZ_QKVW;
        W1a = WPa + SZ_PROJ;
        W2a = W1a + SZ_MLP1;
        sQ = sP = s1 = s2 = 0;
    }

    const int NE = NTOK * EMBED;

    zero_pads<<<WTOK, 256, 0, stream>>>(XWw);
    if (pre) {
        convw_all<<<42144, 256, 0, stream>>>(
            qkv_w, proj_w, mlp_w1, mlp_w2, patch_w, neck_w1, neck_w2,
            WQa, WPa, W1a, W2a, PWb, NW1b, NW2b);
    } else {
        convw_one<<<(73728 + 255) / 256, 256, 0, stream>>>(patch_w, PWb, 768, 73728);
        convw_one<<<(24576 + 255) / 256, 256, 0, stream>>>(neck_w1, NW1b, 768, 24576);
        convw_one<<<(73728 + 255) / 256, 256, 0, stream>>>(neck_w2, NW2b, 2304, 73728);
    }

    // ---- patch embed (tiled A, split-K=2) + fused -> H; LN1 -> windowed ----
    im2col_patch<<<(NE + 255) / 256, 256, 0, stream>>>(x, AOb, NE);
    gemm_rd<0, 2, 6, 1><<<dim3(EMBED / 64, NTOK / 64, 2), 256, 0, stream>>>(
        AOb, PWb, nullptr, SPK, NTOK, EMBED, EMBED, nullptr, 0, 0);
    fuse_ln<2><<<NTOK, 256, 0, stream>>>(
        SPK, (size_t)NTOK * EMBED, 0, pos, patch_b, H, 0, n1w, n1b, XWw, 2);

    for (int i = 0; i < DEPTH; i++) {
        bool glob = (i == 2 || i == 5 || i == 8 || i == 11);
        const unsigned short* wq = WQa + sQ * i;
        const unsigned short* wp = WPa + sP * i;
        const unsigned short* w1 = W1a + s1 * i;
        const unsigned short* w2 = W2a + s2 * i;
        if (!pre) {
            convw_one<<<(221184 + 255) / 256, 256, 0, stream>>>(
                qkv_w + (size_t)i * SZ_QKVW, WQa, 768, 221184);
            convw_one<<<(73728 + 255) / 256, 256, 0, stream>>>(
                proj_w + (size_t)i * SZ_PROJ, WPa, 768, 73728);
            convw_one<<<(294912 + 255) / 256, 256, 0, stream>>>(
                mlp_w1 + (size_t)i * SZ_MLP1, W1a, 768, 294912);
            convw_one<<<(294912 + 255) / 256, 256, 0, stream>>>(
                mlp_w2 + (size_t)i * SZ_MLP2, W2a, 3072, 294912);
        }

        if (!glob) {
            gemm_rd<3, 1, 12, 1><<<dim3(2304 / 64, (WTOK + 63) / 64), 256, 0, stream>>>(
                XWw, wq, qkv_b + i * 2304, QKVb, WTOK, 2304, EMBED, Vt, WN, 208);
            attn_mfma<WN, WINSZ, WINSZ, 208, WPITCH><<<dim3(4, NWIN * HEADS), 256, 0, stream>>>(
                QKVb, Vt, rhw + (size_t)i * 27 * 64, rww + (size_t)i * 27 * 64, AOb);
            gemm_rd<0, 2, 6, 1><<<dim3(EMBED / 64, MPAD / 64, 2), 256, 0, stream>>>(
                AOb, wp, nullptr, SPK, MPAD, EMBED, EMBED, nullptr, 0, 0);
            fuse_ln<2><<<NTOK, 256, 0, stream>>>(
                SPK, (size_t)MPAD * EMBED, 1, nullptr, proj_b + i * EMBED, H, 1,
                n2w + i * EMBED, n2b + i * EMBED, XWs, 1);
        } else {
            gemm_rd<3, 1, 12, 1><<<dim3(2304 / 64, NTOK / 64), 256, 0, stream>>>(
                XWs, wq, qkv_b + i * 2304, QKVb, NTOK, 2304, EMBED, Vt, NTOK, NTOK);
            attn_mfma<NTOK, TOKS, TOKS, NTOK, NTOK><<<dim3(16, HEADS), 256, 0, stream>>>(
                QKVb, Vt, rhg + (size_t)i * 63 * 64, rwg + (size_t)i * 63 * 64, AOb);
            gemm_rd<0, 2, 6, 1><<<dim3(EMBED / 64, NTOK / 64, 2), 256, 0, stream>>>(
                AOb, wp, nullptr, SPK, NTOK, EMBED, EMBED, nullptr, 0, 0);
            fuse_ln<2><<<NTOK, 256, 0, stream>>>(
                SPK, (size_t)NTOK * EMBED, 0, nullptr, proj_b + i * EMBED, H, 1,
                n2w + i * EMBED, n2b + i * EMBED, XWs, 1);
        }
        // MLP (mlp1 -> tiled GELU mid; mlp2 reads tiled A)
        gemm_rd<2, 1, 12, 1><<<dim3(MLPDIM / 64, NTOK / 64), 256, 0, stream>>>(
            XWs, w1, mlp_b1 + i * MLPDIM, MIDB, NTOK, MLPDIM, EMBED, nullptr, 0, 0);
        gemm_rd<0, 4, 12, 1><<<dim3(EMBED / 64, NTOK / 64, 4), 256, 0, stream>>>(
            MIDB, w2, nullptr, SPK, NTOK, EMBED, MLPDIM, nullptr, 0, 0);
        int nlnmode; const float* nw; const float* nb2; unsigned short* ndst;
        if (i == DEPTH - 1) { nlnmode = 3; nw = n1w; nb2 = n1b; ndst = XWs; }
        else {
            bool nglob = (i + 1 == 2 || i + 1 == 5 || i + 1 == 8 || i + 1 == 11);
            nlnmode = nglob ? 1 : 2;
            nw = n1w + (size_t)(i + 1) * EMBED; nb2 = n1b + (size_t)(i + 1) * EMBED;
            ndst = nglob ? XWs : XWw;
        }
        fuse_ln<4><<<NTOK, 256, 0, stream>>>(
            SPK, (size_t)NTOK * EMBED, 0, nullptr, mlp_b2 + i * EMBED, H, 1,
            nw, nb2, ndst, nlnmode);
    }

    // ---- neck ----
    gemm_rd<0, 4, 3, 1><<<dim3(OUTC / 64, NTOK / 64, 4), 256, 0, stream>>>(
        XWs, NW1b, nullptr, SPK, NTOK, OUTC, EMBED, nullptr, 0, 0);
    fuse_ln_neck<4><<<NTOK, 256, 0, stream>>>(SPK, nl1w, nl1b, LNF, NTOK, 0);
    im2col3<<<(NTOK * 2304 + 255) / 256, 256, 0, stream>>>(LNF, CONVA, NTOK * 2304);
    gemm_rd<0, 6, 6, 1><<<dim3(OUTC / 64, NTOK / 64, 6), 256, 0, stream>>>(
        CONVA, NW2b, nullptr, SPK, NTOK, OUTC, 2304, nullptr, 0, 0);
    fuse_ln_neck<6><<<NTOK, 256, 0, stream>>>(SPK, nl2w, nl2b, (float*)d_out, NTOK, 1);
}